// Round 2
// baseline (438.943 us; speedup 1.0000x reference)
//
#include <hip/hip_runtime.h>
#include <hip/hip_bf16.h>

typedef __attribute__((ext_vector_type(8))) __bf16 bf16x8;
typedef __attribute__((ext_vector_type(4))) __bf16 bf16x4;
typedef __attribute__((ext_vector_type(4))) float f32x4;

#define DIM 2048
#define SEQ 2048
#define NH 32
#define NKV 8
#define HD 64
#define KVDIM (NKV * HD)   // 512

// ---------------- fp32 -> bf16 convert (vectorized) ----------------
__global__ void cvt_f32_bf16(const float* __restrict__ in, __bf16* __restrict__ out, int n4) {
    int i = blockIdx.x * blockDim.x + threadIdx.x;
    if (i < n4) {
        float4 v = reinterpret_cast<const float4*>(in)[i];
        bf16x4 o;
        o[0] = (__bf16)v.x; o[1] = (__bf16)v.y; o[2] = (__bf16)v.z; o[3] = (__bf16)v.w;
        reinterpret_cast<bf16x4*>(out)[i] = o;
    }
}

// ---------------- RoPE in-place on bf16 (Q: ncols=2048, K: ncols=512) ----------------
__global__ void rope_kernel(__bf16* __restrict__ q, const float* __restrict__ c,
                            const float* __restrict__ s, int ncols) {
    int row = blockIdx.y;
    int p = blockIdx.x * blockDim.x + threadIdx.x;   // pair index within row
    int i = p & 31;                                   // freq index within head
    __bf16* ptr = q + row * ncols + 2 * p;
    float xr = (float)ptr[0], xi = (float)ptr[1];
    float cc = c[row * 32 + i], ss = s[row * 32 + i];
    ptr[0] = (__bf16)(xr * cc - xi * ss);
    ptr[1] = (__bf16)(xr * ss + xi * cc);
}

// ---------------- TN GEMM: C[M][N] = A[M][K] * B[N][K]^T, bf16 in, fp32 accum ----------
// 128x128 block tile, 4 waves of 64x64, mfma 16x16x32 bf16, frags direct from global.
// OutT = __bf16 for intermediates, float for the final output buffer.
template <typename OutT>
__global__ __launch_bounds__(256) void gemm_tn(const __bf16* __restrict__ A,
                                               const __bf16* __restrict__ B,
                                               OutT* __restrict__ C,
                                               int M, int N, int K) {
    const int tid = threadIdx.x;
    const int lane = tid & 63;
    const int w = tid >> 6;
    const int l15 = lane & 15, lhi = lane >> 4;
    const int mb = blockIdx.y * 128 + (w >> 1) * 64;
    const int nb = blockIdx.x * 128 + (w & 1) * 64;

    f32x4 acc[4][4] = {};
    const __bf16* Ab = A + (size_t)(mb + l15) * K + lhi * 8;
    const __bf16* Bb = B + (size_t)(nb + l15) * K + lhi * 8;

    for (int kk = 0; kk < K; kk += 32) {
        bf16x8 a[4], b[4];
#pragma unroll
        for (int i = 0; i < 4; ++i)
            a[i] = *reinterpret_cast<const bf16x8*>(Ab + (size_t)i * 16 * K + kk);
#pragma unroll
        for (int j = 0; j < 4; ++j)
            b[j] = *reinterpret_cast<const bf16x8*>(Bb + (size_t)j * 16 * K + kk);
#pragma unroll
        for (int i = 0; i < 4; ++i)
#pragma unroll
            for (int j = 0; j < 4; ++j)
                acc[i][j] = __builtin_amdgcn_mfma_f32_16x16x32_bf16(a[i], b[j], acc[i][j], 0, 0, 0);
    }
#pragma unroll
    for (int i = 0; i < 4; ++i)
#pragma unroll
        for (int j = 0; j < 4; ++j)
#pragma unroll
            for (int r = 0; r < 4; ++r)
                C[(size_t)(mb + i * 16 + lhi * 4 + r) * N + nb + j * 16 + l15] = (OutT)acc[i][j][r];
}

// ---------------- Flash attention, causal, GQA rep=4 ----------------
// grid: (SEQ/64 q-tiles, NH heads). 256 threads = 4 waves, wave w owns 16 q rows.
__global__ __launch_bounds__(256) void attn_kernel(const __bf16* __restrict__ Q,
                                                   const __bf16* __restrict__ K,
                                                   const __bf16* __restrict__ V,
                                                   __bf16* __restrict__ Y) {
    const int h = blockIdx.y;
    const int qb = blockIdx.x * 64;
    const int kvh = h >> 2;            // GQA: head h uses kv head h/4
    const int tid = threadIdx.x;
    const int lane = tid & 63;
    const int w = tid >> 6;
    const int l15 = lane & 15, lhi = lane >> 4;

    __shared__ __bf16 Kl[64][72];      // K tile, row-major, padded
    __shared__ __bf16 Vt[64][72];      // V tile, TRANSPOSED [d][kv], padded
    __shared__ __bf16 Pl[4][16][72];   // per-wave P tile

    // Q fragments for this wave's 16 rows (kept in regs across kv loop)
    const __bf16* qrow = Q + (size_t)(qb + w * 16 + l15) * DIM + h * HD;
    bf16x8 qf0 = *reinterpret_cast<const bf16x8*>(qrow + lhi * 8);
    bf16x8 qf1 = *reinterpret_cast<const bf16x8*>(qrow + 32 + lhi * 8);

    f32x4 o[4] = {};
    float m[4], lsum[4];
#pragma unroll
    for (int r = 0; r < 4; ++r) { m[r] = -1e30f; lsum[r] = 0.f; }

    const int jmax = qb / 64;          // inclusive (diagonal tile)
    for (int j = 0; j <= jmax; ++j) {
        __syncthreads();               // prior PV reads done before restage
        {
            const int trow = tid >> 3;
            const int tcb = (tid & 7) * 8;
#pragma unroll
            for (int pass = 0; pass < 2; ++pass) {
                int r = trow + pass * 32;
                const __bf16* kp = K + (size_t)(j * 64 + r) * KVDIM + kvh * HD + tcb;
                bf16x8 k8 = *reinterpret_cast<const bf16x8*>(kp);
                *reinterpret_cast<bf16x8*>(&Kl[r][tcb]) = k8;
                const __bf16* vp = V + (size_t)(j * 64 + r) * KVDIM + kvh * HD + tcb;
                bf16x8 v8 = *reinterpret_cast<const bf16x8*>(vp);
#pragma unroll
                for (int e = 0; e < 8; ++e) Vt[tcb + e][r] = v8[e];
            }
        }
        __syncthreads();

        // S = Q K^T (16 x 64 per wave)
        f32x4 sacc[4];
#pragma unroll
        for (int t = 0; t < 4; ++t) {
            f32x4 z = {0.f, 0.f, 0.f, 0.f};
            bf16x8 kf0 = *reinterpret_cast<const bf16x8*>(&Kl[t * 16 + l15][lhi * 8]);
            bf16x8 kf1 = *reinterpret_cast<const bf16x8*>(&Kl[t * 16 + l15][32 + lhi * 8]);
            z = __builtin_amdgcn_mfma_f32_16x16x32_bf16(qf0, kf0, z, 0, 0, 0);
            z = __builtin_amdgcn_mfma_f32_16x16x32_bf16(qf1, kf1, z, 0, 0, 0);
            sacc[t] = z;
        }

        // scale + causal mask + online softmax
        const int qrow0 = qb + w * 16 + lhi * 4;
        float pmax[4];
#pragma unroll
        for (int r = 0; r < 4; ++r) pmax[r] = -1e30f;
#pragma unroll
        for (int t = 0; t < 4; ++t) {
            int kvcol = j * 64 + t * 16 + l15;
#pragma unroll
            for (int r = 0; r < 4; ++r) {
                float sv = sacc[t][r] * 0.125f;
                if (kvcol > qrow0 + r) sv = -1e30f;
                sacc[t][r] = sv;
                pmax[r] = fmaxf(pmax[r], sv);
            }
        }
#pragma unroll
        for (int r = 0; r < 4; ++r) {
            float v = pmax[r];
            v = fmaxf(v, __shfl_xor(v, 1));
            v = fmaxf(v, __shfl_xor(v, 2));
            v = fmaxf(v, __shfl_xor(v, 4));
            v = fmaxf(v, __shfl_xor(v, 8));
            pmax[r] = v;
        }
        float alpha[4];
#pragma unroll
        for (int r = 0; r < 4; ++r) {
            float mn = fmaxf(m[r], pmax[r]);
            alpha[r] = __expf(m[r] - mn);
            m[r] = mn;
        }
        float psum[4] = {0.f, 0.f, 0.f, 0.f};
#pragma unroll
        for (int t = 0; t < 4; ++t)
#pragma unroll
            for (int r = 0; r < 4; ++r) {
                float p = __expf(sacc[t][r] - m[r]);
                sacc[t][r] = p;
                psum[r] += p;
            }
#pragma unroll
        for (int r = 0; r < 4; ++r) {
            float v = psum[r];
            v += __shfl_xor(v, 1);
            v += __shfl_xor(v, 2);
            v += __shfl_xor(v, 4);
            v += __shfl_xor(v, 8);
            lsum[r] = lsum[r] * alpha[r] + v;
        }
#pragma unroll
        for (int t = 0; t < 4; ++t)
#pragma unroll
            for (int r = 0; r < 4; ++r) o[t][r] *= alpha[r];

        // P -> LDS (bf16)
#pragma unroll
        for (int t = 0; t < 4; ++t)
#pragma unroll
            for (int r = 0; r < 4; ++r)
                Pl[w][lhi * 4 + r][t * 16 + l15] = (__bf16)sacc[t][r];
        __syncthreads();

        // O += P V
        bf16x8 pf0 = *reinterpret_cast<const bf16x8*>(&Pl[w][l15][lhi * 8]);
        bf16x8 pf1 = *reinterpret_cast<const bf16x8*>(&Pl[w][l15][32 + lhi * 8]);
#pragma unroll
        for (int t = 0; t < 4; ++t) {
            bf16x8 vf0 = *reinterpret_cast<const bf16x8*>(&Vt[t * 16 + l15][lhi * 8]);
            bf16x8 vf1 = *reinterpret_cast<const bf16x8*>(&Vt[t * 16 + l15][32 + lhi * 8]);
            o[t] = __builtin_amdgcn_mfma_f32_16x16x32_bf16(pf0, vf0, o[t], 0, 0, 0);
            o[t] = __builtin_amdgcn_mfma_f32_16x16x32_bf16(pf1, vf1, o[t], 0, 0, 0);
        }
    }

    // epilogue: O /= l, store
#pragma unroll
    for (int t = 0; t < 4; ++t)
#pragma unroll
        for (int r = 0; r < 4; ++r) {
            float val = o[t][r] / lsum[r];
            Y[(size_t)(qb + w * 16 + lhi * 4 + r) * DIM + h * HD + t * 16 + l15] = (__bf16)val;
        }
}

extern "C" void kernel_launch(void* const* d_in, const int* in_sizes, int n_in,
                              void* d_out, int out_size, void* d_ws, size_t ws_size,
                              hipStream_t stream) {
    const float* x    = (const float*)d_in[0];
    const float* fcos = (const float*)d_in[1];
    const float* fsin = (const float*)d_in[2];
    const float* wq   = (const float*)d_in[3];
    const float* wk   = (const float*)d_in[4];
    const float* wv   = (const float*)d_in[5];
    const float* wo   = (const float*)d_in[6];
    float* out = (float*)d_out;   // reference output dtype is float32

    __bf16* xb  = (__bf16*)d_ws;
    __bf16* wqb = xb  + (size_t)SEQ * DIM;
    __bf16* wkb = wqb + (size_t)DIM * DIM;
    __bf16* wvb = wkb + (size_t)KVDIM * DIM;
    __bf16* wob = wvb + (size_t)KVDIM * DIM;
    __bf16* Qb  = wob + (size_t)DIM * DIM;
    __bf16* Kb  = Qb  + (size_t)SEQ * DIM;
    __bf16* Vb  = Kb  + (size_t)SEQ * KVDIM;
    __bf16* Yb  = Vb  + (size_t)SEQ * KVDIM;

    const int nx  = SEQ * DIM / 4;     // 1048576
    const int nw  = DIM * DIM / 4;     // 1048576
    const int nkv = KVDIM * DIM / 4;   // 262144
    cvt_f32_bf16<<<(nx + 255) / 256, 256, 0, stream>>>(x, xb, nx);
    cvt_f32_bf16<<<(nw + 255) / 256, 256, 0, stream>>>(wq, wqb, nw);
    cvt_f32_bf16<<<(nkv + 255) / 256, 256, 0, stream>>>(wk, wkb, nkv);
    cvt_f32_bf16<<<(nkv + 255) / 256, 256, 0, stream>>>(wv, wvb, nkv);
    cvt_f32_bf16<<<(nw + 255) / 256, 256, 0, stream>>>(wo, wob, nw);

    gemm_tn<__bf16><<<dim3(DIM / 128, SEQ / 128), 256, 0, stream>>>(xb, wqb, Qb, SEQ, DIM, DIM);
    gemm_tn<__bf16><<<dim3(KVDIM / 128, SEQ / 128), 256, 0, stream>>>(xb, wkb, Kb, SEQ, KVDIM, DIM);
    gemm_tn<__bf16><<<dim3(KVDIM / 128, SEQ / 128), 256, 0, stream>>>(xb, wvb, Vb, SEQ, KVDIM, DIM);

    rope_kernel<<<dim3((DIM / 2) / 256, SEQ), 256, 0, stream>>>(Qb, fcos, fsin, DIM);
    rope_kernel<<<dim3((KVDIM / 2) / 256, SEQ), 256, 0, stream>>>(Kb, fcos, fsin, KVDIM);

    attn_kernel<<<dim3(SEQ / 64, NH), 256, 0, stream>>>(Qb, Kb, Vb, Yb);

    gemm_tn<float><<<dim3(DIM / 128, SEQ / 128), 256, 0, stream>>>(Yb, wob, out, SEQ, DIM, DIM);
}

// Round 3
// 271.223 us; speedup vs baseline: 1.6184x; 1.6184x over previous
//
#include <hip/hip_runtime.h>
#include <hip/hip_bf16.h>

typedef __attribute__((ext_vector_type(8))) __bf16 bf16x8;
typedef __attribute__((ext_vector_type(4))) __bf16 bf16x4;
typedef __attribute__((ext_vector_type(4))) float f32x4;

#define DIM 2048
#define SEQ 2048
#define NH 32
#define NKV 8
#define HD 64
#define QKVD 3072          // 2048 Q | 512 K | 512 V packed columns
#define KOFF 2048
#define VOFF 2560

// async global->LDS, 16B per lane, wave-uniform LDS base (HW: base + lane*16)
__device__ __forceinline__ void gld16(const __bf16* g, __bf16* l) {
    __builtin_amdgcn_global_load_lds(
        (const __attribute__((address_space(1))) void*)g,
        (__attribute__((address_space(3))) void*)l, 16, 0, 0);
}

// ---------------- fp32 -> bf16 convert (vectorized) ----------------
__global__ void cvt_f32_bf16(const float* __restrict__ in, __bf16* __restrict__ out, int n4) {
    int i = blockIdx.x * blockDim.x + threadIdx.x;
    if (i < n4) {
        float4 v = reinterpret_cast<const float4*>(in)[i];
        bf16x4 o;
        o[0] = (__bf16)v.x; o[1] = (__bf16)v.y; o[2] = (__bf16)v.z; o[3] = (__bf16)v.w;
        reinterpret_cast<bf16x4*>(out)[i] = o;
    }
}

// ---------------- RoPE in-place on bf16, row stride `stride` ----------------
__global__ void rope_kernel(__bf16* __restrict__ q, const float* __restrict__ c,
                            const float* __restrict__ s, int stride) {
    int row = blockIdx.y;
    int p = blockIdx.x * blockDim.x + threadIdx.x;   // pair index within row
    int i = p & 31;                                   // freq index within head
    __bf16* ptr = q + (size_t)row * stride + 2 * p;
    float xr = (float)ptr[0], xi = (float)ptr[1];
    float cc = c[row * 32 + i], ss = s[row * 32 + i];
    ptr[0] = (__bf16)(xr * cc - xi * ss);
    ptr[1] = (__bf16)(xr * ss + xi * cc);
}

// ---------------- TN GEMM, m97 structure ----------------
// C[M][N] = scale * A[M][K]*B[N][K]^T. 128x128 tile, BK=32, 4 waves x 64x64,
// global_load_lds width-16 staging, 2 barriers per K-step.
// scale applies only to output cols < scaleNlim (Q region of fused QKV).
template <typename OutT>
__global__ __launch_bounds__(256) void gemm_tn(const __bf16* __restrict__ A,
                                               const __bf16* __restrict__ B,
                                               OutT* __restrict__ C,
                                               int M, int N, int K,
                                               float scale, int scaleNlim) {
    __shared__ __align__(16) __bf16 As[128 * 32];
    __shared__ __align__(16) __bf16 Bs[128 * 32];
    const int tid = threadIdx.x;
    const int lane = tid & 63;
    const int w = tid >> 6;
    const int l15 = lane & 15, lhi = lane >> 4;
    const int mb = blockIdx.y * 128;
    const int nb = blockIdx.x * 128;
    const int wm = (w >> 1) * 64, wn = (w & 1) * 64;

    // staging: chunk c covers rows [c*16, c*16+16) of the 128x32 LDS tile.
    // lane l -> row c*16 + (l>>2), col (l&3)*8  (matches linear lane*16B dest)
    const int srow = lane >> 2, scol = (lane & 3) * 8;
    const __bf16* gA0 = A + (size_t)(mb + w * 16 + srow) * K + scol;
    const __bf16* gA1 = A + (size_t)(mb + (w + 4) * 16 + srow) * K + scol;
    const __bf16* gB0 = B + (size_t)(nb + w * 16 + srow) * K + scol;
    const __bf16* gB1 = B + (size_t)(nb + (w + 4) * 16 + srow) * K + scol;
    __bf16* lA0 = As + w * 512;        // wave-uniform chunk bases
    __bf16* lA1 = As + (w + 4) * 512;
    __bf16* lB0 = Bs + w * 512;
    __bf16* lB1 = Bs + (w + 4) * 512;

    f32x4 acc[4][4] = {};
    for (int kk = 0; kk < K; kk += 32) {
        __syncthreads();               // prior iteration's ds_reads are done
        gld16(gA0 + kk, lA0);
        gld16(gA1 + kk, lA1);
        gld16(gB0 + kk, lB0);
        gld16(gB1 + kk, lB1);
        __syncthreads();               // drains vmcnt -> staged data visible
        bf16x8 a[4], b[4];
#pragma unroll
        for (int i = 0; i < 4; ++i)
            a[i] = *reinterpret_cast<const bf16x8*>(&As[(wm + i * 16 + l15) * 32 + lhi * 8]);
#pragma unroll
        for (int j = 0; j < 4; ++j)
            b[j] = *reinterpret_cast<const bf16x8*>(&Bs[(wn + j * 16 + l15) * 32 + lhi * 8]);
#pragma unroll
        for (int i = 0; i < 4; ++i)
#pragma unroll
            for (int j = 0; j < 4; ++j)
                acc[i][j] = __builtin_amdgcn_mfma_f32_16x16x32_bf16(a[i], b[j], acc[i][j], 0, 0, 0);
    }
    const float sc = (nb < scaleNlim) ? scale : 1.0f;
#pragma unroll
    for (int i = 0; i < 4; ++i)
#pragma unroll
        for (int j = 0; j < 4; ++j)
#pragma unroll
            for (int r = 0; r < 4; ++r)
                C[(size_t)(mb + wm + i * 16 + lhi * 4 + r) * N + nb + wn + j * 16 + l15] =
                    (OutT)(acc[i][j][r] * sc);
}

// ---------------- Flash attention, causal, GQA rep=4 ----------------
// Block: 128 q-rows x 1 head, 4 waves x 32 rows. KV tile = 64.
// Q/K/V read from fused QKV[2048][3072]. Scores pre-scaled via Q-proj.
__global__ __launch_bounds__(256) void attn_kernel(const __bf16* __restrict__ QKV,
                                                   __bf16* __restrict__ Y) {
    const int h = blockIdx.y;
    const int qt = (SEQ / 128 - 1) - blockIdx.x;   // heavy tiles first
    const int qb = qt * 128;
    const int kvh = h >> 2;
    const int tid = threadIdx.x;
    const int lane = tid & 63;
    const int w = tid >> 6;
    const int l15 = lane & 15, lhi = lane >> 4;

    __shared__ __align__(16) __bf16 Kl[64][72];       // K tile row-major, pad 72
    __shared__ __align__(16) __bf16 Vt[64][72];       // V^T, kv block-XOR swizzled
    __shared__ __align__(16) __bf16 Pl[4][32][72];    // per-wave P tile

    const __bf16* Qp = QKV + h * HD;
    const __bf16* Kp = QKV + KOFF + kvh * HD;
    const __bf16* Vp = QKV + VOFF + kvh * HD;

    bf16x8 qf[2][2];
#pragma unroll
    for (int g = 0; g < 2; ++g) {
        const __bf16* qrow = Qp + (size_t)(qb + w * 32 + g * 16 + l15) * QKVD;
        qf[g][0] = *reinterpret_cast<const bf16x8*>(qrow + lhi * 8);
        qf[g][1] = *reinterpret_cast<const bf16x8*>(qrow + 32 + lhi * 8);
    }

    f32x4 o[2][4] = {};
    float m[2][4], lsum[2][4];
#pragma unroll
    for (int g = 0; g < 2; ++g)
#pragma unroll
        for (int r = 0; r < 4; ++r) { m[g][r] = -1e30f; lsum[g][r] = 0.f; }

    const int jmax = qb / 64 + 1;
    for (int j = 0; j <= jmax; ++j) {
        __syncthreads();               // prior PV reads done before restage
        {
            const int trow = tid >> 3;
            const int g8 = (tid & 7) * 8;
#pragma unroll
            for (int pass = 0; pass < 2; ++pass) {
                const int r = trow + pass * 32;
                bf16x8 k8 = *reinterpret_cast<const bf16x8*>(Kp + (size_t)(j * 64 + r) * QKVD + g8);
                *reinterpret_cast<bf16x8*>(&Kl[r][g8]) = k8;
                bf16x8 v8 = *reinterpret_cast<const bf16x8*>(Vp + (size_t)(j * 64 + r) * QKVD + g8);
#pragma unroll
                for (int e = 0; e < 8; ++e) {
                    const int d = g8 + e;
                    Vt[d][r ^ ((d >> 3) << 3)] = v8[e];   // block-XOR: ~2-way max
                }
            }
        }
        __syncthreads();

        // S = Q K^T : per wave 32 rows x 64 cols
        f32x4 sacc[2][4];
#pragma unroll
        for (int t = 0; t < 4; ++t) {
            bf16x8 kf0 = *reinterpret_cast<const bf16x8*>(&Kl[t * 16 + l15][lhi * 8]);
            bf16x8 kf1 = *reinterpret_cast<const bf16x8*>(&Kl[t * 16 + l15][32 + lhi * 8]);
#pragma unroll
            for (int g = 0; g < 2; ++g) {
                f32x4 z = {0.f, 0.f, 0.f, 0.f};
                z = __builtin_amdgcn_mfma_f32_16x16x32_bf16(qf[g][0], kf0, z, 0, 0, 0);
                z = __builtin_amdgcn_mfma_f32_16x16x32_bf16(qf[g][1], kf1, z, 0, 0, 0);
                sacc[g][t] = z;
            }
        }

        // causal mask + online softmax (scores already scaled by 1/8 in Q-proj)
#pragma unroll
        for (int g = 0; g < 2; ++g) {
            const int qrow0 = qb + w * 32 + g * 16 + lhi * 4;
            float pmax[4] = {-1e30f, -1e30f, -1e30f, -1e30f};
#pragma unroll
            for (int t = 0; t < 4; ++t) {
                const int kvcol = j * 64 + t * 16 + l15;
#pragma unroll
                for (int r = 0; r < 4; ++r) {
                    float sv = sacc[g][t][r];
                    if (kvcol > qrow0 + r) sv = -1e30f;
                    sacc[g][t][r] = sv;
                    pmax[r] = fmaxf(pmax[r], sv);
                }
            }
#pragma unroll
            for (int r = 0; r < 4; ++r) {
                float v = pmax[r];
                v = fmaxf(v, __shfl_xor(v, 1));
                v = fmaxf(v, __shfl_xor(v, 2));
                v = fmaxf(v, __shfl_xor(v, 4));
                v = fmaxf(v, __shfl_xor(v, 8));
                pmax[r] = v;
            }
            float alpha[4];
#pragma unroll
            for (int r = 0; r < 4; ++r) {
                const float mn = fmaxf(m[g][r], pmax[r]);
                alpha[r] = __expf(m[g][r] - mn);
                m[g][r] = mn;
            }
            float psum[4] = {0.f, 0.f, 0.f, 0.f};
#pragma unroll
            for (int t = 0; t < 4; ++t)
#pragma unroll
                for (int r = 0; r < 4; ++r) {
                    const float p = __expf(sacc[g][t][r] - m[g][r]);
                    sacc[g][t][r] = p;
                    psum[r] += p;
                }
#pragma unroll
            for (int r = 0; r < 4; ++r) {
                float v = psum[r];
                v += __shfl_xor(v, 1);
                v += __shfl_xor(v, 2);
                v += __shfl_xor(v, 4);
                v += __shfl_xor(v, 8);
                lsum[g][r] = lsum[g][r] * alpha[r] + v;
            }
#pragma unroll
            for (int t = 0; t < 4; ++t)
#pragma unroll
                for (int r = 0; r < 4; ++r) o[g][t][r] *= alpha[r];
            // P -> LDS (wave-private: no barrier needed, lgkmcnt orders it)
#pragma unroll
            for (int t = 0; t < 4; ++t)
#pragma unroll
                for (int r = 0; r < 4; ++r)
                    Pl[w][g * 16 + lhi * 4 + r][t * 16 + l15] = (__bf16)sacc[g][t][r];
        }

        // O += P V
        bf16x8 pf[2][2];
#pragma unroll
        for (int g = 0; g < 2; ++g) {
            pf[g][0] = *reinterpret_cast<const bf16x8*>(&Pl[w][g * 16 + l15][lhi * 8]);
            pf[g][1] = *reinterpret_cast<const bf16x8*>(&Pl[w][g * 16 + l15][32 + lhi * 8]);
        }
#pragma unroll
        for (int t = 0; t < 4; ++t) {
            const int drow = t * 16 + l15;
            const int b0 = (lhi ^ (drow >> 3)) * 8;
            const int b1 = ((4 + lhi) ^ (drow >> 3)) * 8;
            bf16x8 vf0 = *reinterpret_cast<const bf16x8*>(&Vt[drow][b0]);
            bf16x8 vf1 = *reinterpret_cast<const bf16x8*>(&Vt[drow][b1]);
#pragma unroll
            for (int g = 0; g < 2; ++g) {
                o[g][t] = __builtin_amdgcn_mfma_f32_16x16x32_bf16(pf[g][0], vf0, o[g][t], 0, 0, 0);
                o[g][t] = __builtin_amdgcn_mfma_f32_16x16x32_bf16(pf[g][1], vf1, o[g][t], 0, 0, 0);
            }
        }
    }

    // epilogue
#pragma unroll
    for (int g = 0; g < 2; ++g)
#pragma unroll
        for (int t = 0; t < 4; ++t)
#pragma unroll
            for (int r = 0; r < 4; ++r) {
                const float val = o[g][t][r] / lsum[g][r];
                Y[(size_t)(qb + w * 32 + g * 16 + lhi * 4 + r) * DIM + h * HD + t * 16 + l15] =
                    (__bf16)val;
            }
}

extern "C" void kernel_launch(void* const* d_in, const int* in_sizes, int n_in,
                              void* d_out, int out_size, void* d_ws, size_t ws_size,
                              hipStream_t stream) {
    const float* x    = (const float*)d_in[0];
    const float* fcos = (const float*)d_in[1];
    const float* fsin = (const float*)d_in[2];
    const float* wq   = (const float*)d_in[3];
    const float* wk   = (const float*)d_in[4];
    const float* wv   = (const float*)d_in[5];
    const float* wo   = (const float*)d_in[6];
    float* out = (float*)d_out;

    __bf16* xb    = (__bf16*)d_ws;                       // [2048][2048]
    __bf16* wqkvb = xb + (size_t)SEQ * DIM;              // [3072][2048]
    __bf16* wob   = wqkvb + (size_t)QKVD * DIM;          // [2048][2048]
    __bf16* QKVb  = wob + (size_t)DIM * DIM;             // [2048][3072]
    __bf16* Yb    = QKVb + (size_t)SEQ * QKVD;           // [2048][2048]

    const int nx  = SEQ * DIM / 4;
    const int nw  = DIM * DIM / 4;
    const int nkv = (NKV * HD) * DIM / 4;
    cvt_f32_bf16<<<(nx + 255) / 256, 256, 0, stream>>>(x, xb, nx);
    cvt_f32_bf16<<<(nw + 255) / 256, 256, 0, stream>>>(wq, wqkvb, nw);
    cvt_f32_bf16<<<(nkv + 255) / 256, 256, 0, stream>>>(wk, wqkvb + (size_t)KOFF * DIM, nkv);
    cvt_f32_bf16<<<(nkv + 255) / 256, 256, 0, stream>>>(wv, wqkvb + (size_t)VOFF * DIM, nkv);
    cvt_f32_bf16<<<(nw + 255) / 256, 256, 0, stream>>>(wo, wob, nw);

    // fused QKV projection; Q columns pre-scaled by 1/sqrt(64)
    gemm_tn<__bf16><<<dim3(QKVD / 128, SEQ / 128), 256, 0, stream>>>(
        xb, wqkvb, QKVb, SEQ, QKVD, DIM, 0.125f, KOFF);

    rope_kernel<<<dim3((DIM / 2) / 256, SEQ), 256, 0, stream>>>(QKVb, fcos, fsin, QKVD);
    rope_kernel<<<dim3(((NKV * HD) / 2) / 256, SEQ), 256, 0, stream>>>(QKVb + KOFF, fcos, fsin, QKVD);

    attn_kernel<<<dim3(SEQ / 128, NH), 256, 0, stream>>>(QKVb, Yb);

    gemm_tn<float><<<dim3(DIM / 128, SEQ / 128), 256, 0, stream>>>(
        Yb, wob, out, SEQ, DIM, DIM, 1.0f, 0);
}

// Round 4
// 217.404 us; speedup vs baseline: 2.0190x; 1.2475x over previous
//
#include <hip/hip_runtime.h>
#include <hip/hip_bf16.h>

typedef __attribute__((ext_vector_type(8))) __bf16 bf16x8;
typedef __attribute__((ext_vector_type(4))) __bf16 bf16x4;
typedef __attribute__((ext_vector_type(4))) float f32x4;

#define DIM 2048
#define SEQ 2048
#define NH 32
#define NKV 8
#define HD 64
#define QKVD 3072          // 2048 Q | 512 K | 512 V packed columns
#define KOFF 2048
#define VOFF 2560

// async global->LDS, 16B per lane, wave-uniform LDS base (HW: base + lane*16)
__device__ __forceinline__ void gld16(const __bf16* g, __bf16* l) {
    __builtin_amdgcn_global_load_lds(
        (const __attribute__((address_space(1))) void*)g,
        (__attribute__((address_space(3))) void*)l, 16, 0, 0);
}

// ---------------- fp32 -> bf16 convert (vectorized) ----------------
__global__ void cvt_f32_bf16(const float* __restrict__ in, __bf16* __restrict__ out, int n4) {
    int i = blockIdx.x * blockDim.x + threadIdx.x;
    if (i < n4) {
        float4 v = reinterpret_cast<const float4*>(in)[i];
        bf16x4 o;
        o[0] = (__bf16)v.x; o[1] = (__bf16)v.y; o[2] = (__bf16)v.z; o[3] = (__bf16)v.w;
        reinterpret_cast<bf16x4*>(out)[i] = o;
    }
}

// ---------------- RoPE in-place on bf16, row stride `stride` ----------------
__global__ void rope_kernel(__bf16* __restrict__ q, const float* __restrict__ c,
                            const float* __restrict__ s, int stride) {
    int row = blockIdx.y;
    int p = blockIdx.x * blockDim.x + threadIdx.x;   // pair index within row
    int i = p & 31;                                   // freq index within head
    __bf16* ptr = q + (size_t)row * stride + 2 * p;
    float xr = (float)ptr[0], xi = (float)ptr[1];
    float cc = c[row * 32 + i], ss = s[row * 32 + i];
    ptr[0] = (__bf16)(xr * cc - xi * ss);
    ptr[1] = (__bf16)(xr * ss + xi * cc);
}

// ---------------- TN GEMM, m97 structure (unchanged from round 3) ----------
template <typename OutT>
__global__ __launch_bounds__(256) void gemm_tn(const __bf16* __restrict__ A,
                                               const __bf16* __restrict__ B,
                                               OutT* __restrict__ C,
                                               int M, int N, int K,
                                               float scale, int scaleNlim) {
    __shared__ __align__(16) __bf16 As[128 * 32];
    __shared__ __align__(16) __bf16 Bs[128 * 32];
    const int tid = threadIdx.x;
    const int lane = tid & 63;
    const int w = tid >> 6;
    const int l15 = lane & 15, lhi = lane >> 4;
    const int mb = blockIdx.y * 128;
    const int nb = blockIdx.x * 128;
    const int wm = (w >> 1) * 64, wn = (w & 1) * 64;

    const int srow = lane >> 2, scol = (lane & 3) * 8;
    const __bf16* gA0 = A + (size_t)(mb + w * 16 + srow) * K + scol;
    const __bf16* gA1 = A + (size_t)(mb + (w + 4) * 16 + srow) * K + scol;
    const __bf16* gB0 = B + (size_t)(nb + w * 16 + srow) * K + scol;
    const __bf16* gB1 = B + (size_t)(nb + (w + 4) * 16 + srow) * K + scol;
    __bf16* lA0 = As + w * 512;
    __bf16* lA1 = As + (w + 4) * 512;
    __bf16* lB0 = Bs + w * 512;
    __bf16* lB1 = Bs + (w + 4) * 512;

    f32x4 acc[4][4] = {};
    for (int kk = 0; kk < K; kk += 32) {
        __syncthreads();
        gld16(gA0 + kk, lA0);
        gld16(gA1 + kk, lA1);
        gld16(gB0 + kk, lB0);
        gld16(gB1 + kk, lB1);
        __syncthreads();
        bf16x8 a[4], b[4];
#pragma unroll
        for (int i = 0; i < 4; ++i)
            a[i] = *reinterpret_cast<const bf16x8*>(&As[(wm + i * 16 + l15) * 32 + lhi * 8]);
#pragma unroll
        for (int j = 0; j < 4; ++j)
            b[j] = *reinterpret_cast<const bf16x8*>(&Bs[(wn + j * 16 + l15) * 32 + lhi * 8]);
#pragma unroll
        for (int i = 0; i < 4; ++i)
#pragma unroll
            for (int j = 0; j < 4; ++j)
                acc[i][j] = __builtin_amdgcn_mfma_f32_16x16x32_bf16(a[i], b[j], acc[i][j], 0, 0, 0);
    }
    const float sc = (nb < scaleNlim) ? scale : 1.0f;
#pragma unroll
    for (int i = 0; i < 4; ++i)
#pragma unroll
        for (int j = 0; j < 4; ++j)
#pragma unroll
            for (int r = 0; r < 4; ++r)
                C[(size_t)(mb + wm + i * 16 + lhi * 4 + r) * N + nb + wn + j * 16 + l15] =
                    (OutT)(acc[i][j][r] * sc);
}

// ---------------- Flash attention: swapped QK^T, in-lane softmax ------------
// Block: 128 q-rows x 1 head, 4 waves x 32 rows. KV tile 64, double-buffered.
// Scores arrive in log2-units (Q pre-scaled by 0.125*log2(e)); exp2 softmax.
// sacc layout (swapped mfma(K,Q)): lane owns q = g*16 + (lane&15);
//   kv = t*16 + (lane>>4)*4 + r.   o layout (normal PV): q = g*16+(lane>>4)*4+r,
//   d = t*16 + (lane&15).
__global__ __launch_bounds__(256) void attn_kernel(const __bf16* __restrict__ QKV,
                                                   __bf16* __restrict__ Y) {
    const int h = blockIdx.y;
    const int qt = (SEQ / 128 - 1) - blockIdx.x;   // heavy tiles first
    const int qb = qt * 128;
    const int kvh = h >> 2;
    const int tid = threadIdx.x;
    const int lane = tid & 63;
    const int w = tid >> 6;
    const int l15 = lane & 15, lhi = lane >> 4;

    __shared__ __align__(16) __bf16 Kl[2][64][72];
    __shared__ __align__(16) __bf16 Vt[2][64][72];    // V^T, kv block-XOR swizzled
    __shared__ __align__(16) __bf16 Pl[4][32][72];

    const __bf16* Qp = QKV + h * HD;
    const __bf16* Kp = QKV + KOFF + kvh * HD;
    const __bf16* Vp = QKV + VOFF + kvh * HD;

    // Q fragments (B-operand of swapped QK^T): row=q_local=g*16+l15, k=d
    bf16x8 qf[2][2];
#pragma unroll
    for (int g = 0; g < 2; ++g) {
        const __bf16* qrow = Qp + (size_t)(qb + w * 32 + g * 16 + l15) * QKVD;
        qf[g][0] = *reinterpret_cast<const bf16x8*>(qrow + lhi * 8);
        qf[g][1] = *reinterpret_cast<const bf16x8*>(qrow + 32 + lhi * 8);
    }

    f32x4 o[2][4] = {};
    float m[2] = {-1e30f, -1e30f};
    float lsum[2] = {0.f, 0.f};

    // staging mapping: thread -> kv row (0..63), d chunk base (0/16/32/48)
    const int srow = tid >> 2;
    const int sd0 = (tid & 3) * 16;

    const int jmax = qb / 64 + 1;

    // prologue: stage tile 0 into buffer 0
    {
        const __bf16* kr = Kp + (size_t)srow * QKVD;
        const __bf16* vr = Vp + (size_t)srow * QKVD;
        bf16x8 k0 = *reinterpret_cast<const bf16x8*>(kr + sd0);
        bf16x8 k1 = *reinterpret_cast<const bf16x8*>(kr + sd0 + 8);
        bf16x8 v0 = *reinterpret_cast<const bf16x8*>(vr + sd0);
        bf16x8 v1 = *reinterpret_cast<const bf16x8*>(vr + sd0 + 8);
        *reinterpret_cast<bf16x8*>(&Kl[0][srow][sd0]) = k0;
        *reinterpret_cast<bf16x8*>(&Kl[0][srow][sd0 + 8]) = k1;
#pragma unroll
        for (int e = 0; e < 8; ++e) {
            const int d0 = sd0 + e, d1 = sd0 + 8 + e;
            Vt[0][d0][srow ^ ((d0 >> 3) << 3)] = v0[e];
            Vt[0][d1][srow ^ ((d1 >> 3) << 3)] = v1[e];
        }
    }
    __syncthreads();

    int cur = 0;
    for (int j = 0; j <= jmax; ++j, cur ^= 1) {
        // ---- T14: issue next tile's global loads early (land under compute)
        bf16x8 k0, k1, v0, v1;
        const bool pre = (j < jmax);
        if (pre) {
            const __bf16* kr = Kp + (size_t)((j + 1) * 64 + srow) * QKVD;
            const __bf16* vr = Vp + (size_t)((j + 1) * 64 + srow) * QKVD;
            k0 = *reinterpret_cast<const bf16x8*>(kr + sd0);
            k1 = *reinterpret_cast<const bf16x8*>(kr + sd0 + 8);
            v0 = *reinterpret_cast<const bf16x8*>(vr + sd0);
            v1 = *reinterpret_cast<const bf16x8*>(vr + sd0 + 8);
        }

        // ---- S^T = K Q^T (swapped): sacc[g][t] row=kv col=q
        f32x4 sacc[2][4];
#pragma unroll
        for (int t = 0; t < 4; ++t) {
            bf16x8 kf0 = *reinterpret_cast<const bf16x8*>(&Kl[cur][t * 16 + l15][lhi * 8]);
            bf16x8 kf1 = *reinterpret_cast<const bf16x8*>(&Kl[cur][t * 16 + l15][32 + lhi * 8]);
#pragma unroll
            for (int g = 0; g < 2; ++g) {
                f32x4 z = {0.f, 0.f, 0.f, 0.f};
                z = __builtin_amdgcn_mfma_f32_16x16x32_bf16(kf0, qf[g][0], z, 0, 0, 0);
                z = __builtin_amdgcn_mfma_f32_16x16x32_bf16(kf1, qf[g][1], z, 0, 0, 0);
                sacc[g][t] = z;
            }
        }

        // ---- softmax, per-lane scalar state (lane owns one q per g)
#pragma unroll
        for (int g = 0; g < 2; ++g) {
            const int qrow = qb + w * 32 + g * 16 + l15;
            if (j * 64 + 63 > qb + w * 32 + g * 16) {     // tile needs masking
#pragma unroll
                for (int t = 0; t < 4; ++t)
#pragma unroll
                    for (int r = 0; r < 4; ++r) {
                        const int kv = j * 64 + t * 16 + lhi * 4 + r;
                        if (kv > qrow) sacc[g][t][r] = -1e30f;
                    }
            }
            float pm = sacc[g][0][0];
#pragma unroll
            for (int t = 0; t < 4; ++t)
#pragma unroll
                for (int r = 0; r < 4; ++r) pm = fmaxf(pm, sacc[g][t][r]);
            pm = fmaxf(pm, __shfl_xor(pm, 16));
            pm = fmaxf(pm, __shfl_xor(pm, 32));

            if (!__all(pm - m[g] <= 8.0f)) {              // T13 defer-max
                const float mn = fmaxf(m[g], pm);
                const float a = exp2f(m[g] - mn);
                m[g] = mn;
                lsum[g] *= a;
                float ar[4];
#pragma unroll
                for (int r = 0; r < 4; ++r) ar[r] = __shfl(a, lhi * 4 + r);
#pragma unroll
                for (int t = 0; t < 4; ++t)
#pragma unroll
                    for (int r = 0; r < 4; ++r) o[g][t][r] *= ar[r];
            }

            float ps = 0.f;
#pragma unroll
            for (int t = 0; t < 4; ++t) {
                bf16x4 pk;
#pragma unroll
                for (int r = 0; r < 4; ++r) {
                    const float p = exp2f(sacc[g][t][r] - m[g]);
                    ps += p;
                    pk[r] = (__bf16)p;
                }
                *reinterpret_cast<bf16x4*>(&Pl[w][g * 16 + l15][t * 16 + lhi * 4]) = pk;
            }
            ps += __shfl_xor(ps, 16);
            ps += __shfl_xor(ps, 32);
            lsum[g] += ps;
        }

        // ---- O += P V (normal orientation; P via LDS relayout)
        bf16x8 pf[2][2];
#pragma unroll
        for (int g = 0; g < 2; ++g) {
            pf[g][0] = *reinterpret_cast<const bf16x8*>(&Pl[w][g * 16 + l15][lhi * 8]);
            pf[g][1] = *reinterpret_cast<const bf16x8*>(&Pl[w][g * 16 + l15][32 + lhi * 8]);
        }
#pragma unroll
        for (int t = 0; t < 4; ++t) {
            const int drow = t * 16 + l15;
            bf16x8 vf0 = *reinterpret_cast<const bf16x8*>(&Vt[cur][drow][(lhi ^ (drow >> 3)) * 8]);
            bf16x8 vf1 = *reinterpret_cast<const bf16x8*>(&Vt[cur][drow][((4 + lhi) ^ (drow >> 3)) * 8]);
#pragma unroll
            for (int g = 0; g < 2; ++g) {
                o[g][t] = __builtin_amdgcn_mfma_f32_16x16x32_bf16(pf[g][0], vf0, o[g][t], 0, 0, 0);
                o[g][t] = __builtin_amdgcn_mfma_f32_16x16x32_bf16(pf[g][1], vf1, o[g][t], 0, 0, 0);
            }
        }

        // ---- write staged regs to the other buffer, single barrier
        if (pre) {
            const int nxt = cur ^ 1;
            *reinterpret_cast<bf16x8*>(&Kl[nxt][srow][sd0]) = k0;
            *reinterpret_cast<bf16x8*>(&Kl[nxt][srow][sd0 + 8]) = k1;
#pragma unroll
            for (int e = 0; e < 8; ++e) {
                const int d0 = sd0 + e, d1 = sd0 + 8 + e;
                Vt[nxt][d0][srow ^ ((d0 >> 3) << 3)] = v0[e];
                Vt[nxt][d1][srow ^ ((d1 >> 3) << 3)] = v1[e];
            }
        }
        __syncthreads();
    }

    // ---- epilogue: redistribute lsum (swapped->o layout), divide, store
#pragma unroll
    for (int g = 0; g < 2; ++g) {
        float ls[4];
#pragma unroll
        for (int r = 0; r < 4; ++r) ls[r] = __shfl(lsum[g], lhi * 4 + r);
#pragma unroll
        for (int t = 0; t < 4; ++t)
#pragma unroll
            for (int r = 0; r < 4; ++r) {
                const float val = o[g][t][r] / ls[r];
                Y[(size_t)(qb + w * 32 + g * 16 + lhi * 4 + r) * DIM + h * HD + t * 16 + l15] =
                    (__bf16)val;
            }
    }
}

extern "C" void kernel_launch(void* const* d_in, const int* in_sizes, int n_in,
                              void* d_out, int out_size, void* d_ws, size_t ws_size,
                              hipStream_t stream) {
    const float* x    = (const float*)d_in[0];
    const float* fcos = (const float*)d_in[1];
    const float* fsin = (const float*)d_in[2];
    const float* wq   = (const float*)d_in[3];
    const float* wk   = (const float*)d_in[4];
    const float* wv   = (const float*)d_in[5];
    const float* wo   = (const float*)d_in[6];
    float* out = (float*)d_out;

    __bf16* xb    = (__bf16*)d_ws;                       // [2048][2048]
    __bf16* wqkvb = xb + (size_t)SEQ * DIM;              // [3072][2048]
    __bf16* wob   = wqkvb + (size_t)QKVD * DIM;          // [2048][2048]
    __bf16* QKVb  = wob + (size_t)DIM * DIM;             // [2048][3072]
    __bf16* Yb    = QKVb + (size_t)SEQ * QKVD;           // [2048][2048]

    const int nx  = SEQ * DIM / 4;
    const int nw  = DIM * DIM / 4;
    const int nkv = (NKV * HD) * DIM / 4;
    cvt_f32_bf16<<<(nx + 255) / 256, 256, 0, stream>>>(x, xb, nx);
    cvt_f32_bf16<<<(nw + 255) / 256, 256, 0, stream>>>(wq, wqkvb, nw);
    cvt_f32_bf16<<<(nkv + 255) / 256, 256, 0, stream>>>(wk, wqkvb + (size_t)KOFF * DIM, nkv);
    cvt_f32_bf16<<<(nkv + 255) / 256, 256, 0, stream>>>(wv, wqkvb + (size_t)VOFF * DIM, nkv);
    cvt_f32_bf16<<<(nw + 255) / 256, 256, 0, stream>>>(wo, wob, nw);

    // fused QKV projection; Q pre-scaled by (1/sqrt(64)) * log2(e) (exp2 softmax)
    gemm_tn<__bf16><<<dim3(QKVD / 128, SEQ / 128), 256, 0, stream>>>(
        xb, wqkvb, QKVb, SEQ, QKVD, DIM, 0.125f * 1.4426950408889634f, KOFF);

    rope_kernel<<<dim3((DIM / 2) / 256, SEQ), 256, 0, stream>>>(QKVb, fcos, fsin, QKVD);
    rope_kernel<<<dim3(((NKV * HD) / 2) / 256, SEQ), 256, 0, stream>>>(QKVb + KOFF, fcos, fsin, QKVD);

    attn_kernel<<<dim3(SEQ / 128, NH), 256, 0, stream>>>(QKVb, Yb);

    gemm_tn<float><<<dim3(DIM / 128, SEQ / 128), 256, 0, stream>>>(
        Yb, wob, out, SEQ, DIM, DIM, 1.0f, 0);
}

// Round 5
// 195.809 us; speedup vs baseline: 2.2417x; 1.1103x over previous
//
#include <hip/hip_runtime.h>
#include <hip/hip_bf16.h>

typedef __attribute__((ext_vector_type(8))) __bf16 bf16x8;
typedef __attribute__((ext_vector_type(4))) __bf16 bf16x4;
typedef __attribute__((ext_vector_type(4))) float f32x4;

#define DIM 2048
#define SEQ 2048
#define NH 32
#define NKV 8
#define HD 64
#define QKVD 3072          // 2048 Q | 512 K | 512 V packed columns
#define KOFF 2048
#define VOFF 2560

// async global->LDS, 16B per lane, wave-uniform LDS base (HW: base + lane*16)
__device__ __forceinline__ void gld16(const __bf16* g, __bf16* l) {
    __builtin_amdgcn_global_load_lds(
        (const __attribute__((address_space(1))) void*)g,
        (__attribute__((address_space(3))) void*)l, 16, 0, 0);
}

// ---------------- fp32 -> bf16 convert (vectorized) ----------------
__global__ void cvt_f32_bf16(const float* __restrict__ in, __bf16* __restrict__ out, int n4) {
    int i = blockIdx.x * blockDim.x + threadIdx.x;
    if (i < n4) {
        float4 v = reinterpret_cast<const float4*>(in)[i];
        bf16x4 o;
        o[0] = (__bf16)v.x; o[1] = (__bf16)v.y; o[2] = (__bf16)v.z; o[3] = (__bf16)v.w;
        reinterpret_cast<bf16x4*>(out)[i] = o;
    }
}

// ---------------- RoPE in-place on bf16, row stride `stride` ----------------
__global__ void rope_kernel(__bf16* __restrict__ q, const float* __restrict__ c,
                            const float* __restrict__ s, int stride) {
    int row = blockIdx.y;
    int p = blockIdx.x * blockDim.x + threadIdx.x;   // pair index within row
    int i = p & 31;                                   // freq index within head
    __bf16* ptr = q + (size_t)row * stride + 2 * p;
    float xr = (float)ptr[0], xi = (float)ptr[1];
    float cc = c[row * 32 + i], ss = s[row * 32 + i];
    ptr[0] = (__bf16)(xr * cc - xi * ss);
    ptr[1] = (__bf16)(xr * ss + xi * cc);
}

// ---------------- TN GEMM, m97 structure (unchanged) ----------
template <typename OutT>
__global__ __launch_bounds__(256) void gemm_tn(const __bf16* __restrict__ A,
                                               const __bf16* __restrict__ B,
                                               OutT* __restrict__ C,
                                               int M, int N, int K,
                                               float scale, int scaleNlim) {
    __shared__ __align__(16) __bf16 As[128 * 32];
    __shared__ __align__(16) __bf16 Bs[128 * 32];
    const int tid = threadIdx.x;
    const int lane = tid & 63;
    const int w = tid >> 6;
    const int l15 = lane & 15, lhi = lane >> 4;
    const int mb = blockIdx.y * 128;
    const int nb = blockIdx.x * 128;
    const int wm = (w >> 1) * 64, wn = (w & 1) * 64;

    const int srow = lane >> 2, scol = (lane & 3) * 8;
    const __bf16* gA0 = A + (size_t)(mb + w * 16 + srow) * K + scol;
    const __bf16* gA1 = A + (size_t)(mb + (w + 4) * 16 + srow) * K + scol;
    const __bf16* gB0 = B + (size_t)(nb + w * 16 + srow) * K + scol;
    const __bf16* gB1 = B + (size_t)(nb + (w + 4) * 16 + srow) * K + scol;
    __bf16* lA0 = As + w * 512;
    __bf16* lA1 = As + (w + 4) * 512;
    __bf16* lB0 = Bs + w * 512;
    __bf16* lB1 = Bs + (w + 4) * 512;

    f32x4 acc[4][4] = {};
    for (int kk = 0; kk < K; kk += 32) {
        __syncthreads();
        gld16(gA0 + kk, lA0);
        gld16(gA1 + kk, lA1);
        gld16(gB0 + kk, lB0);
        gld16(gB1 + kk, lB1);
        __syncthreads();
        bf16x8 a[4], b[4];
#pragma unroll
        for (int i = 0; i < 4; ++i)
            a[i] = *reinterpret_cast<const bf16x8*>(&As[(wm + i * 16 + l15) * 32 + lhi * 8]);
#pragma unroll
        for (int j = 0; j < 4; ++j)
            b[j] = *reinterpret_cast<const bf16x8*>(&Bs[(wn + j * 16 + l15) * 32 + lhi * 8]);
#pragma unroll
        for (int i = 0; i < 4; ++i)
#pragma unroll
            for (int j = 0; j < 4; ++j)
                acc[i][j] = __builtin_amdgcn_mfma_f32_16x16x32_bf16(a[i], b[j], acc[i][j], 0, 0, 0);
    }
    const float sc = (nb < scaleNlim) ? scale : 1.0f;
#pragma unroll
    for (int i = 0; i < 4; ++i)
#pragma unroll
        for (int j = 0; j < 4; ++j)
#pragma unroll
            for (int r = 0; r < 4; ++r)
                C[(size_t)(mb + wm + i * 16 + lhi * 4 + r) * N + nb + wn + j * 16 + l15] =
                    (OutT)(acc[i][j][r] * sc);
}

// ---------------- Flash attention: swapped QK^T, in-lane softmax ------------
// Flat grid 512. qt/h decode makes pair-sums of kv-work equal (15 tiles) for
// BOTH adjacent (x^1) and stride-256 (x+256) block pairings -> balanced CUs.
__global__ __launch_bounds__(256) void attn_kernel(const __bf16* __restrict__ QKV,
                                                   __bf16* __restrict__ Y) {
    const int bx = blockIdx.x;
    const int sel = (bx ^ (bx >> 8)) & 1;
    const int k8 = (bx >> 5) & 7;
    const int qt = sel ? k8 : 15 - k8;
    const int h = ((bx >> 1) & 15) | (((bx >> 8) & 1) << 4);
    const int qb = qt * 128;
    const int kvh = h >> 2;
    const int tid = threadIdx.x;
    const int lane = tid & 63;
    const int w = tid >> 6;
    const int l15 = lane & 15, lhi = lane >> 4;

    __shared__ __align__(16) __bf16 Kl[2][64][72];
    __shared__ __align__(16) __bf16 Vt[2][64][72];    // V^T, kv block-XOR swizzled
    __shared__ __align__(16) __bf16 Pl[4][32][72];

    const __bf16* Qp = QKV + h * HD;
    const __bf16* Kp = QKV + KOFF + kvh * HD;
    const __bf16* Vp = QKV + VOFF + kvh * HD;

    // Q fragments (B-operand of swapped QK^T): row=q_local=g*16+l15, k=d
    bf16x8 qf[2][2];
#pragma unroll
    for (int g = 0; g < 2; ++g) {
        const __bf16* qrow = Qp + (size_t)(qb + w * 32 + g * 16 + l15) * QKVD;
        qf[g][0] = *reinterpret_cast<const bf16x8*>(qrow + lhi * 8);
        qf[g][1] = *reinterpret_cast<const bf16x8*>(qrow + 32 + lhi * 8);
    }

    f32x4 o[2][4] = {};
    float m[2] = {-1e30f, -1e30f};
    float lsum[2] = {0.f, 0.f};

    // staging mapping: thread -> kv row (0..63), d chunk base (0/16/32/48)
    const int srow = tid >> 2;
    const int sd0 = (tid & 3) * 16;

    const int jmax = qb / 64 + 1;

    // prologue: stage tile 0 into buffer 0
    {
        const __bf16* kr = Kp + (size_t)srow * QKVD;
        const __bf16* vr = Vp + (size_t)srow * QKVD;
        bf16x8 k0 = *reinterpret_cast<const bf16x8*>(kr + sd0);
        bf16x8 k1 = *reinterpret_cast<const bf16x8*>(kr + sd0 + 8);
        bf16x8 v0 = *reinterpret_cast<const bf16x8*>(vr + sd0);
        bf16x8 v1 = *reinterpret_cast<const bf16x8*>(vr + sd0 + 8);
        *reinterpret_cast<bf16x8*>(&Kl[0][srow][sd0]) = k0;
        *reinterpret_cast<bf16x8*>(&Kl[0][srow][sd0 + 8]) = k1;
#pragma unroll
        for (int e = 0; e < 8; ++e) {
            const int d0 = sd0 + e, d1 = sd0 + 8 + e;
            Vt[0][d0][srow ^ ((d0 >> 3) << 3)] = v0[e];
            Vt[0][d1][srow ^ ((d1 >> 3) << 3)] = v1[e];
        }
    }
    __syncthreads();

    int cur = 0;
    for (int j = 0; j <= jmax; ++j, cur ^= 1) {
        // ---- T14: issue next tile's global loads early (land under compute)
        bf16x8 k0, k1, v0, v1;
        const bool pre = (j < jmax);
        if (pre) {
            const __bf16* kr = Kp + (size_t)((j + 1) * 64 + srow) * QKVD;
            const __bf16* vr = Vp + (size_t)((j + 1) * 64 + srow) * QKVD;
            k0 = *reinterpret_cast<const bf16x8*>(kr + sd0);
            k1 = *reinterpret_cast<const bf16x8*>(kr + sd0 + 8);
            v0 = *reinterpret_cast<const bf16x8*>(vr + sd0);
            v1 = *reinterpret_cast<const bf16x8*>(vr + sd0 + 8);
        }

        // ---- S^T = K Q^T (swapped): sacc[g][t] row=kv col=q
        f32x4 sacc[2][4];
        __builtin_amdgcn_s_setprio(1);
#pragma unroll
        for (int t = 0; t < 4; ++t) {
            bf16x8 kf0 = *reinterpret_cast<const bf16x8*>(&Kl[cur][t * 16 + l15][lhi * 8]);
            bf16x8 kf1 = *reinterpret_cast<const bf16x8*>(&Kl[cur][t * 16 + l15][32 + lhi * 8]);
#pragma unroll
            for (int g = 0; g < 2; ++g) {
                f32x4 z = {0.f, 0.f, 0.f, 0.f};
                z = __builtin_amdgcn_mfma_f32_16x16x32_bf16(kf0, qf[g][0], z, 0, 0, 0);
                z = __builtin_amdgcn_mfma_f32_16x16x32_bf16(kf1, qf[g][1], z, 0, 0, 0);
                sacc[g][t] = z;
            }
        }
        __builtin_amdgcn_s_setprio(0);

        // ---- softmax, per-lane scalar state (lane owns one q per g)
#pragma unroll
        for (int g = 0; g < 2; ++g) {
            const int qrow = qb + w * 32 + g * 16 + l15;
            if (j * 64 + 63 > qb + w * 32 + g * 16) {     // tile needs masking
#pragma unroll
                for (int t = 0; t < 4; ++t)
#pragma unroll
                    for (int r = 0; r < 4; ++r) {
                        const int kv = j * 64 + t * 16 + lhi * 4 + r;
                        if (kv > qrow) sacc[g][t][r] = -1e30f;
                    }
            }
            // shallow max tree (v_max3-friendly)
            float mt[4];
#pragma unroll
            for (int t = 0; t < 4; ++t)
                mt[t] = fmaxf(fmaxf(sacc[g][t][0], sacc[g][t][1]),
                              fmaxf(sacc[g][t][2], sacc[g][t][3]));
            float pm = fmaxf(fmaxf(mt[0], mt[1]), fmaxf(mt[2], mt[3]));
            pm = fmaxf(pm, __shfl_xor(pm, 16));
            pm = fmaxf(pm, __shfl_xor(pm, 32));

            if (!__all(pm - m[g] <= 8.0f)) {              // T13 defer-max
                const float mn = fmaxf(m[g], pm);
                const float a = exp2f(m[g] - mn);
                m[g] = mn;
                lsum[g] *= a;
                float ar[4];
#pragma unroll
                for (int r = 0; r < 4; ++r) ar[r] = __shfl(a, lhi * 4 + r);
#pragma unroll
                for (int t = 0; t < 4; ++t)
#pragma unroll
                    for (int r = 0; r < 4; ++r) o[g][t][r] *= ar[r];
            }

            float ps = 0.f;
#pragma unroll
            for (int t = 0; t < 4; ++t) {
                bf16x4 pk;
#pragma unroll
                for (int r = 0; r < 4; ++r) {
                    const float p = exp2f(sacc[g][t][r] - m[g]);
                    ps += p;
                    pk[r] = (__bf16)p;
                }
                *reinterpret_cast<bf16x4*>(&Pl[w][g * 16 + l15][t * 16 + lhi * 4]) = pk;
            }
            ps += __shfl_xor(ps, 16);
            ps += __shfl_xor(ps, 32);
            lsum[g] += ps;
        }

        // ---- O += P V (normal orientation; P via LDS relayout)
        bf16x8 pf[2][2];
#pragma unroll
        for (int g = 0; g < 2; ++g) {
            pf[g][0] = *reinterpret_cast<const bf16x8*>(&Pl[w][g * 16 + l15][lhi * 8]);
            pf[g][1] = *reinterpret_cast<const bf16x8*>(&Pl[w][g * 16 + l15][32 + lhi * 8]);
        }
        __builtin_amdgcn_s_setprio(1);
#pragma unroll
        for (int t = 0; t < 4; ++t) {
            const int drow = t * 16 + l15;
            bf16x8 vf0 = *reinterpret_cast<const bf16x8*>(&Vt[cur][drow][(lhi ^ (drow >> 3)) * 8]);
            bf16x8 vf1 = *reinterpret_cast<const bf16x8*>(&Vt[cur][drow][((4 + lhi) ^ (drow >> 3)) * 8]);
#pragma unroll
            for (int g = 0; g < 2; ++g) {
                o[g][t] = __builtin_amdgcn_mfma_f32_16x16x32_bf16(pf[g][0], vf0, o[g][t], 0, 0, 0);
                o[g][t] = __builtin_amdgcn_mfma_f32_16x16x32_bf16(pf[g][1], vf1, o[g][t], 0, 0, 0);
            }
        }
        __builtin_amdgcn_s_setprio(0);

        // ---- write staged regs to the other buffer, single barrier
        if (pre) {
            const int nxt = cur ^ 1;
            *reinterpret_cast<bf16x8*>(&Kl[nxt][srow][sd0]) = k0;
            *reinterpret_cast<bf16x8*>(&Kl[nxt][srow][sd0 + 8]) = k1;
#pragma unroll
            for (int e = 0; e < 8; ++e) {
                const int d0 = sd0 + e, d1 = sd0 + 8 + e;
                Vt[nxt][d0][srow ^ ((d0 >> 3) << 3)] = v0[e];
                Vt[nxt][d1][srow ^ ((d1 >> 3) << 3)] = v1[e];
            }
        }
        __syncthreads();
    }

    // ---- epilogue: redistribute lsum (swapped->o layout), divide, store
#pragma unroll
    for (int g = 0; g < 2; ++g) {
        float ls[4];
#pragma unroll
        for (int r = 0; r < 4; ++r) ls[r] = __shfl(lsum[g], lhi * 4 + r);
#pragma unroll
        for (int t = 0; t < 4; ++t)
#pragma unroll
            for (int r = 0; r < 4; ++r) {
                const float val = o[g][t][r] / ls[r];
                Y[(size_t)(qb + w * 32 + g * 16 + lhi * 4 + r) * DIM + h * HD + t * 16 + l15] =
                    (__bf16)val;
            }
    }
}

extern "C" void kernel_launch(void* const* d_in, const int* in_sizes, int n_in,
                              void* d_out, int out_size, void* d_ws, size_t ws_size,
                              hipStream_t stream) {
    const float* x    = (const float*)d_in[0];
    const float* fcos = (const float*)d_in[1];
    const float* fsin = (const float*)d_in[2];
    const float* wq   = (const float*)d_in[3];
    const float* wk   = (const float*)d_in[4];
    const float* wv   = (const float*)d_in[5];
    const float* wo   = (const float*)d_in[6];
    float* out = (float*)d_out;

    __bf16* xb    = (__bf16*)d_ws;                       // [2048][2048]
    __bf16* wqkvb = xb + (size_t)SEQ * DIM;              // [3072][2048]
    __bf16* wob   = wqkvb + (size_t)QKVD * DIM;          // [2048][2048]
    __bf16* QKVb  = wob + (size_t)DIM * DIM;             // [2048][3072]
    __bf16* Yb    = QKVb + (size_t)SEQ * QKVD;           // [2048][2048]

    const int nx  = SEQ * DIM / 4;
    const int nw  = DIM * DIM / 4;
    const int nkv = (NKV * HD) * DIM / 4;
    cvt_f32_bf16<<<(nx + 255) / 256, 256, 0, stream>>>(x, xb, nx);
    cvt_f32_bf16<<<(nw + 255) / 256, 256, 0, stream>>>(wq, wqkvb, nw);
    cvt_f32_bf16<<<(nkv + 255) / 256, 256, 0, stream>>>(wk, wqkvb + (size_t)KOFF * DIM, nkv);
    cvt_f32_bf16<<<(nkv + 255) / 256, 256, 0, stream>>>(wv, wqkvb + (size_t)VOFF * DIM, nkv);
    cvt_f32_bf16<<<(nw + 255) / 256, 256, 0, stream>>>(wo, wob, nw);

    // fused QKV projection; Q pre-scaled by (1/sqrt(64)) * log2(e) (exp2 softmax)
    gemm_tn<__bf16><<<dim3(QKVD / 128, SEQ / 128), 256, 0, stream>>>(
        xb, wqkvb, QKVb, SEQ, QKVD, DIM, 0.125f * 1.4426950408889634f, KOFF);

    rope_kernel<<<dim3((DIM / 2) / 256, SEQ), 256, 0, stream>>>(QKVb, fcos, fsin, QKVD);
    rope_kernel<<<dim3(((NKV * HD) / 2) / 256, SEQ), 256, 0, stream>>>(QKVb + KOFF, fcos, fsin, QKVD);

    attn_kernel<<<dim3(512), 256, 0, stream>>>(QKVb, Yb);

    gemm_tn<float><<<dim3(DIM / 128, SEQ / 128), 256, 0, stream>>>(
        Yb, wob, out, SEQ, DIM, DIM, 1.0f, 0);
}

// Round 6
// 175.654 us; speedup vs baseline: 2.4989x; 1.1147x over previous
//
#include <hip/hip_runtime.h>
#include <hip/hip_bf16.h>

typedef __attribute__((ext_vector_type(8))) __bf16 bf16x8;
typedef __attribute__((ext_vector_type(4))) __bf16 bf16x4;
typedef __attribute__((ext_vector_type(4))) float f32x4;

#define DIM 2048
#define SEQ 2048
#define NH 32
#define NKV 8
#define HD 64
#define QKVD 3072          // 2048 Q | 512 K | 512 V packed columns
#define KOFF 2048
#define VOFF 2560

// async global->LDS, 16B per lane, wave-uniform LDS base (HW: base + lane*16)
__device__ __forceinline__ void gld16(const __bf16* g, __bf16* l) {
    __builtin_amdgcn_global_load_lds(
        (const __attribute__((address_space(1))) void*)g,
        (__attribute__((address_space(3))) void*)l, 16, 0, 0);
}

// ---------------- fp32 -> bf16 convert (vectorized) ----------------
__global__ void cvt_f32_bf16(const float* __restrict__ in, __bf16* __restrict__ out, int n4) {
    int i = blockIdx.x * blockDim.x + threadIdx.x;
    if (i < n4) {
        float4 v = reinterpret_cast<const float4*>(in)[i];
        bf16x4 o;
        o[0] = (__bf16)v.x; o[1] = (__bf16)v.y; o[2] = (__bf16)v.z; o[3] = (__bf16)v.w;
        reinterpret_cast<bf16x4*>(out)[i] = o;
    }
}

// ---------------- RoPE in-place on bf16, row stride `stride` ----------------
__global__ void rope_kernel(__bf16* __restrict__ q, const float* __restrict__ c,
                            const float* __restrict__ s, int stride) {
    int row = blockIdx.y;
    int p = blockIdx.x * blockDim.x + threadIdx.x;   // pair index within row
    int i = p & 31;                                   // freq index within head
    __bf16* ptr = q + (size_t)row * stride + 2 * p;
    float xr = (float)ptr[0], xi = (float)ptr[1];
    float cc = c[row * 32 + i], ss = s[row * 32 + i];
    ptr[0] = (__bf16)(xr * cc - xi * ss);
    ptr[1] = (__bf16)(xr * ss + xi * cc);
}

// ---------------- TN GEMM: 128x64 tile, 4 waves x (64x32), BK=32 -------------
// Grid integral blocks/CU: N=3072 -> 768 blocks (3/CU), N=2048 -> 512 (2/CU).
template <typename OutT>
__global__ __launch_bounds__(256) void gemm_tn(const __bf16* __restrict__ A,
                                               const __bf16* __restrict__ B,
                                               OutT* __restrict__ C,
                                               int M, int N, int K,
                                               float scale, int scaleNlim) {
    __shared__ __align__(16) __bf16 As[128 * 32];
    __shared__ __align__(16) __bf16 Bs[64 * 32];
    const int tid = threadIdx.x;
    const int lane = tid & 63;
    const int w = tid >> 6;
    const int l15 = lane & 15, lhi = lane >> 4;
    const int mb = blockIdx.y * 128;
    const int nb = blockIdx.x * 64;
    const int wm = (w >> 1) * 64, wn = (w & 1) * 32;

    // staging: chunk c = rows [c*16, c*16+16) of a [rows][32] LDS tile.
    // lane l -> row c*16 + (l>>2), col (l&3)*8 (linear lane*16B dest)
    const int srow = lane >> 2, scol = (lane & 3) * 8;
    const __bf16* gA0 = A + (size_t)(mb + w * 16 + srow) * K + scol;
    const __bf16* gA1 = A + (size_t)(mb + (w + 4) * 16 + srow) * K + scol;
    const __bf16* gB0 = B + (size_t)(nb + w * 16 + srow) * K + scol;
    __bf16* lA0 = As + w * 512;
    __bf16* lA1 = As + (w + 4) * 512;
    __bf16* lB0 = Bs + w * 512;

    f32x4 acc[4][2] = {};
    for (int kk = 0; kk < K; kk += 32) {
        __syncthreads();
        gld16(gA0 + kk, lA0);
        gld16(gA1 + kk, lA1);
        gld16(gB0 + kk, lB0);
        __syncthreads();
        bf16x8 a[4], b[2];
#pragma unroll
        for (int i = 0; i < 4; ++i)
            a[i] = *reinterpret_cast<const bf16x8*>(&As[(wm + i * 16 + l15) * 32 + lhi * 8]);
#pragma unroll
        for (int j = 0; j < 2; ++j)
            b[j] = *reinterpret_cast<const bf16x8*>(&Bs[(wn + j * 16 + l15) * 32 + lhi * 8]);
#pragma unroll
        for (int i = 0; i < 4; ++i)
#pragma unroll
            for (int j = 0; j < 2; ++j)
                acc[i][j] = __builtin_amdgcn_mfma_f32_16x16x32_bf16(a[i], b[j], acc[i][j], 0, 0, 0);
    }
    const float sc = (nb < scaleNlim) ? scale : 1.0f;
#pragma unroll
    for (int i = 0; i < 4; ++i)
#pragma unroll
        for (int j = 0; j < 2; ++j)
#pragma unroll
            for (int r = 0; r < 4; ++r)
                C[(size_t)(mb + wm + i * 16 + lhi * 4 + r) * N + nb + wn + j * 16 + l15] =
                    (OutT)(acc[i][j][r] * sc);
}

// ---------------- Flash attention: equal-work blocks, swapped QK^T ----------
// Grid 512: block = (pair p, head h) processes q-tiles p and 31-p (64 rows
// each, 4 waves x 16 rows) sequentially -> every block = 33 kv-iterations.
// Steady-state softmax is shuffle-free: per-lane partial max drives the
// defer-max check; row-sum kept as per-lane partials combined in epilogue.
__global__ __launch_bounds__(256) void attn_kernel(const __bf16* __restrict__ QKV,
                                                   __bf16* __restrict__ Y) {
    const int bx = blockIdx.x;
    const int p = bx >> 5;         // 0..15
    const int h = bx & 31;
    const int kvh = h >> 2;
    const int tid = threadIdx.x;
    const int lane = tid & 63;
    const int w = tid >> 6;
    const int l15 = lane & 15, lhi = lane >> 4;

    __shared__ __align__(16) __bf16 Kl[2][64][72];
    __shared__ __align__(16) __bf16 Vt[2][64][72];    // V^T, kv block-XOR swizzled
    __shared__ __align__(16) __bf16 Pl[4][16][72];

    const __bf16* Qp = QKV + h * HD;
    const __bf16* Kp = QKV + KOFF + kvh * HD;
    const __bf16* Vp = QKV + VOFF + kvh * HD;

    // staging mapping: thread -> kv row (0..63), d chunk base (0/16/32/48)
    const int srow = tid >> 2;
    const int sd0 = (tid & 3) * 16;

    for (int seg = 0; seg < 2; ++seg) {
        const int qt = seg ? (31 - p) : p;
        const int qb = qt * 64;
        const int mtile = qt;                  // inclusive kv-tile bound
        const int qrow = qb + w * 16 + l15;    // this lane's q (swapped layout)

        // Q fragments (B-operand of swapped QK^T)
        const __bf16* qptr = Qp + (size_t)qrow * QKVD;
        bf16x8 qf0 = *reinterpret_cast<const bf16x8*>(qptr + lhi * 8);
        bf16x8 qf1 = *reinterpret_cast<const bf16x8*>(qptr + 32 + lhi * 8);

        f32x4 o[4] = {};
        float mrun = -1e30f;
        float lpart = 0.f;                     // per-lane partial row-sum

        // prologue: stage kv tile 0 into buffer 0
        {
            const __bf16* kr = Kp + (size_t)srow * QKVD;
            const __bf16* vr = Vp + (size_t)srow * QKVD;
            bf16x8 k0 = *reinterpret_cast<const bf16x8*>(kr + sd0);
            bf16x8 k1 = *reinterpret_cast<const bf16x8*>(kr + sd0 + 8);
            bf16x8 v0 = *reinterpret_cast<const bf16x8*>(vr + sd0);
            bf16x8 v1 = *reinterpret_cast<const bf16x8*>(vr + sd0 + 8);
            *reinterpret_cast<bf16x8*>(&Kl[0][srow][sd0]) = k0;
            *reinterpret_cast<bf16x8*>(&Kl[0][srow][sd0 + 8]) = k1;
#pragma unroll
            for (int e = 0; e < 8; ++e) {
                const int d0 = sd0 + e, d1 = sd0 + 8 + e;
                Vt[0][d0][srow ^ ((d0 >> 3) << 3)] = v0[e];
                Vt[0][d1][srow ^ ((d1 >> 3) << 3)] = v1[e];
            }
        }
        __syncthreads();

        int cur = 0;
        for (int j = 0; j <= mtile; ++j, cur ^= 1) {
            // T14: issue next tile's global loads early
            bf16x8 k0, k1, v0, v1;
            const bool pre = (j < mtile);
            if (pre) {
                const __bf16* kr = Kp + (size_t)((j + 1) * 64 + srow) * QKVD;
                const __bf16* vr = Vp + (size_t)((j + 1) * 64 + srow) * QKVD;
                k0 = *reinterpret_cast<const bf16x8*>(kr + sd0);
                k1 = *reinterpret_cast<const bf16x8*>(kr + sd0 + 8);
                v0 = *reinterpret_cast<const bf16x8*>(vr + sd0);
                v1 = *reinterpret_cast<const bf16x8*>(vr + sd0 + 8);
            }

            // S^T = K Q^T (swapped): lane owns q=l15; kv = t*16 + lhi*4 + r
            f32x4 sacc[4];
            __builtin_amdgcn_s_setprio(1);
#pragma unroll
            for (int t = 0; t < 4; ++t) {
                bf16x8 kf0 = *reinterpret_cast<const bf16x8*>(&Kl[cur][t * 16 + l15][lhi * 8]);
                bf16x8 kf1 = *reinterpret_cast<const bf16x8*>(&Kl[cur][t * 16 + l15][32 + lhi * 8]);
                f32x4 z = {0.f, 0.f, 0.f, 0.f};
                z = __builtin_amdgcn_mfma_f32_16x16x32_bf16(kf0, qf0, z, 0, 0, 0);
                z = __builtin_amdgcn_mfma_f32_16x16x32_bf16(kf1, qf1, z, 0, 0, 0);
                sacc[t] = z;
            }
            __builtin_amdgcn_s_setprio(0);

            // causal mask: only the diagonal tile needs it
            if (j == mtile) {
#pragma unroll
                for (int t = 0; t < 4; ++t)
#pragma unroll
                    for (int r = 0; r < 4; ++r) {
                        const int kv = j * 64 + t * 16 + lhi * 4 + r;
                        if (kv > qrow) sacc[t][r] = -1e30f;
                    }
            }

            // per-lane partial max (no cross-lane in steady state)
            float mt[4];
#pragma unroll
            for (int t = 0; t < 4; ++t)
                mt[t] = fmaxf(fmaxf(sacc[t][0], sacc[t][1]),
                              fmaxf(sacc[t][2], sacc[t][3]));
            const float pm = fmaxf(fmaxf(mt[0], mt[1]), fmaxf(mt[2], mt[3]));

            if (!__all(pm - mrun <= 8.0f)) {           // T13 defer-max
                float full = pm;
                full = fmaxf(full, __shfl_xor(full, 16));
                full = fmaxf(full, __shfl_xor(full, 32));
                const float mn = fmaxf(mrun, full);    // uniform across q's 4 lanes
                const float a = exp2f(mrun - mn);
                mrun = mn;
                lpart *= a;
                float ar[4];
#pragma unroll
                for (int r = 0; r < 4; ++r) ar[r] = __shfl(a, lhi * 4 + r);
#pragma unroll
                for (int t = 0; t < 4; ++t)
#pragma unroll
                    for (int r = 0; r < 4; ++r) o[t][r] *= ar[r];
            }

            // P = exp2(S - m), partial sum, pack to LDS
#pragma unroll
            for (int t = 0; t < 4; ++t) {
                bf16x4 pk;
#pragma unroll
                for (int r = 0; r < 4; ++r) {
                    const float pv = exp2f(sacc[t][r] - mrun);
                    lpart += pv;
                    pk[r] = (__bf16)pv;
                }
                *reinterpret_cast<bf16x4*>(&Pl[w][l15][t * 16 + lhi * 4]) = pk;
            }

            // O += P V (same-wave DS ordering: write->read in order)
            bf16x8 pf0 = *reinterpret_cast<const bf16x8*>(&Pl[w][l15][lhi * 8]);
            bf16x8 pf1 = *reinterpret_cast<const bf16x8*>(&Pl[w][l15][32 + lhi * 8]);
            __builtin_amdgcn_s_setprio(1);
#pragma unroll
            for (int t = 0; t < 4; ++t) {
                const int drow = t * 16 + l15;
                bf16x8 vf0 = *reinterpret_cast<const bf16x8*>(
                    &Vt[cur][drow][(lhi ^ (drow >> 3)) * 8]);
                bf16x8 vf1 = *reinterpret_cast<const bf16x8*>(
                    &Vt[cur][drow][((4 + lhi) ^ (drow >> 3)) * 8]);
                o[t] = __builtin_amdgcn_mfma_f32_16x16x32_bf16(pf0, vf0, o[t], 0, 0, 0);
                o[t] = __builtin_amdgcn_mfma_f32_16x16x32_bf16(pf1, vf1, o[t], 0, 0, 0);
            }
            __builtin_amdgcn_s_setprio(0);

            // write prefetched tile to the other buffer, single barrier
            if (pre) {
                const int nxt = cur ^ 1;
                *reinterpret_cast<bf16x8*>(&Kl[nxt][srow][sd0]) = k0;
                *reinterpret_cast<bf16x8*>(&Kl[nxt][srow][sd0 + 8]) = k1;
#pragma unroll
                for (int e = 0; e < 8; ++e) {
                    const int d0 = sd0 + e, d1 = sd0 + 8 + e;
                    Vt[nxt][d0][srow ^ ((d0 >> 3) << 3)] = v0[e];
                    Vt[nxt][d1][srow ^ ((d1 >> 3) << 3)] = v1[e];
                }
            }
            __syncthreads();
        }

        // epilogue: combine partial sums (2 shuffles, once), divide, store
        float ls = lpart;
        ls += __shfl_xor(ls, 16);
        ls += __shfl_xor(ls, 32);              // lsum for q=l15, uniform over lhi
        float lr[4];
#pragma unroll
        for (int r = 0; r < 4; ++r) lr[r] = __shfl(ls, lhi * 4 + r);
#pragma unroll
        for (int t = 0; t < 4; ++t)
#pragma unroll
            for (int r = 0; r < 4; ++r) {
                const float val = o[t][r] / lr[r];
                Y[(size_t)(qb + w * 16 + lhi * 4 + r) * DIM + h * HD + t * 16 + l15] =
                    (__bf16)val;
            }
    }
}

extern "C" void kernel_launch(void* const* d_in, const int* in_sizes, int n_in,
                              void* d_out, int out_size, void* d_ws, size_t ws_size,
                              hipStream_t stream) {
    const float* x    = (const float*)d_in[0];
    const float* fcos = (const float*)d_in[1];
    const float* fsin = (const float*)d_in[2];
    const float* wq   = (const float*)d_in[3];
    const float* wk   = (const float*)d_in[4];
    const float* wv   = (const float*)d_in[5];
    const float* wo   = (const float*)d_in[6];
    float* out = (float*)d_out;

    __bf16* xb    = (__bf16*)d_ws;                       // [2048][2048]
    __bf16* wqkvb = xb + (size_t)SEQ * DIM;              // [3072][2048]
    __bf16* wob   = wqkvb + (size_t)QKVD * DIM;          // [2048][2048]
    __bf16* QKVb  = wob + (size_t)DIM * DIM;             // [2048][3072]
    __bf16* Yb    = QKVb + (size_t)SEQ * QKVD;           // [2048][2048]

    const int nx  = SEQ * DIM / 4;
    const int nw  = DIM * DIM / 4;
    const int nkv = (NKV * HD) * DIM / 4;
    cvt_f32_bf16<<<(nx + 255) / 256, 256, 0, stream>>>(x, xb, nx);
    cvt_f32_bf16<<<(nw + 255) / 256, 256, 0, stream>>>(wq, wqkvb, nw);
    cvt_f32_bf16<<<(nkv + 255) / 256, 256, 0, stream>>>(wk, wqkvb + (size_t)KOFF * DIM, nkv);
    cvt_f32_bf16<<<(nkv + 255) / 256, 256, 0, stream>>>(wv, wqkvb + (size_t)VOFF * DIM, nkv);
    cvt_f32_bf16<<<(nw + 255) / 256, 256, 0, stream>>>(wo, wob, nw);

    // fused QKV projection; Q pre-scaled by (1/sqrt(64)) * log2(e) (exp2 softmax)
    gemm_tn<__bf16><<<dim3(QKVD / 64, SEQ / 128), 256, 0, stream>>>(
        xb, wqkvb, QKVb, SEQ, QKVD, DIM, 0.125f * 1.4426950408889634f, KOFF);

    rope_kernel<<<dim3((DIM / 2) / 256, SEQ), 256, 0, stream>>>(QKVb, fcos, fsin, QKVD);
    rope_kernel<<<dim3(((NKV * HD) / 2) / 256, SEQ), 256, 0, stream>>>(QKVb + KOFF, fcos, fsin, QKVD);

    attn_kernel<<<dim3(512), 256, 0, stream>>>(QKVb, Yb);

    gemm_tn<float><<<dim3(DIM / 64, SEQ / 128), 256, 0, stream>>>(
        Yb, wob, out, SEQ, DIM, DIM, 1.0f, 0);
}

// Round 7
// 170.697 us; speedup vs baseline: 2.5715x; 1.0290x over previous
//
#include <hip/hip_runtime.h>
#include <hip/hip_bf16.h>

typedef __attribute__((ext_vector_type(8))) __bf16 bf16x8;
typedef __attribute__((ext_vector_type(4))) __bf16 bf16x4;
typedef __attribute__((ext_vector_type(4))) float f32x4;

#define DIM 2048
#define SEQ 2048
#define NH 32
#define NKV 8
#define HD 64
#define QKVD 3072          // 2048 Q | 512 K | 512 V packed columns
#define KOFF 2048
#define VOFF 2560
#define KVDIM 512

// async global->LDS, 16B per lane, wave-uniform LDS base (HW: base + lane*16)
__device__ __forceinline__ void gld16(const __bf16* g, __bf16* l) {
    __builtin_amdgcn_global_load_lds(
        (const __attribute__((address_space(1))) void*)g,
        (__attribute__((address_space(3))) void*)l, 16, 0, 0);
}

// ---------------- fp32 -> bf16 convert (vectorized) ----------------
__global__ void cvt_f32_bf16(const float* __restrict__ in, __bf16* __restrict__ out, int n4) {
    int i = blockIdx.x * blockDim.x + threadIdx.x;
    if (i < n4) {
        float4 v = reinterpret_cast<const float4*>(in)[i];
        bf16x4 o;
        o[0] = (__bf16)v.x; o[1] = (__bf16)v.y; o[2] = (__bf16)v.z; o[3] = (__bf16)v.w;
        reinterpret_cast<bf16x4*>(out)[i] = o;
    }
}

// ---------------- RoPE in-place on bf16, row stride `stride` ----------------
__global__ void rope_kernel(__bf16* __restrict__ q, const float* __restrict__ c,
                            const float* __restrict__ s, int stride) {
    int row = blockIdx.y;
    int p = blockIdx.x * blockDim.x + threadIdx.x;   // pair index within row
    int i = p & 31;                                   // freq index within head
    __bf16* ptr = q + (size_t)row * stride + 2 * p;
    float xr = (float)ptr[0], xi = (float)ptr[1];
    float cc = c[row * 32 + i], ss = s[row * 32 + i];
    ptr[0] = (__bf16)(xr * cc - xi * ss);
    ptr[1] = (__bf16)(xr * ss + xi * cc);
}

// ---------------- V transpose: V[seq][512] -> VT[512][seq] (one-shot) -------
__global__ __launch_bounds__(256) void transpose_v(const __bf16* __restrict__ V,
                                                   __bf16* __restrict__ VT) {
    __shared__ __bf16 t[64][72];
    const int tid = threadIdx.x;
    const int r = tid >> 2, c0 = (tid & 3) * 16;
    const int sb = blockIdx.x * 64;   // seq base
    const int db = blockIdx.y * 64;   // d base
    bf16x8 a0 = *reinterpret_cast<const bf16x8*>(V + (size_t)(sb + r) * QKVD + db + c0);
    bf16x8 a1 = *reinterpret_cast<const bf16x8*>(V + (size_t)(sb + r) * QKVD + db + c0 + 8);
#pragma unroll
    for (int e = 0; e < 8; ++e) { t[c0 + e][r] = a0[e]; t[c0 + 8 + e][r] = a1[e]; }
    __syncthreads();
    bf16x8 o0 = *reinterpret_cast<const bf16x8*>(&t[r][c0]);
    bf16x8 o1 = *reinterpret_cast<const bf16x8*>(&t[r][c0 + 8]);
    *reinterpret_cast<bf16x8*>(VT + (size_t)(db + r) * SEQ + sb + c0) = o0;
    *reinterpret_cast<bf16x8*>(VT + (size_t)(db + r) * SEQ + sb + c0 + 8) = o1;
}

// ---------------- TN GEMM: 128x64 tile, dbuf single-barrier (T3-min) --------
template <typename OutT>
__global__ __launch_bounds__(256) void gemm_tn(const __bf16* __restrict__ A,
                                               const __bf16* __restrict__ B,
                                               OutT* __restrict__ C,
                                               int M, int N, int K,
                                               float scale, int scaleNlim) {
    __shared__ __align__(16) __bf16 As[2][128 * 32];
    __shared__ __align__(16) __bf16 Bs[2][64 * 32];
    const int tid = threadIdx.x;
    const int lane = tid & 63;
    const int w = tid >> 6;
    const int l15 = lane & 15, lhi = lane >> 4;
    const int mb = blockIdx.y * 128;
    const int nb = blockIdx.x * 64;
    const int wm = (w >> 1) * 64, wn = (w & 1) * 32;

    const int srow = lane >> 2, scol = (lane & 3) * 8;
    const __bf16* gA0 = A + (size_t)(mb + w * 16 + srow) * K + scol;
    const __bf16* gA1 = A + (size_t)(mb + (w + 4) * 16 + srow) * K + scol;
    const __bf16* gB0 = B + (size_t)(nb + w * 16 + srow) * K + scol;

    // prologue: stage k-tile 0 into buffer 0
    gld16(gA0, As[0] + w * 512);
    gld16(gA1, As[0] + (w + 4) * 512);
    gld16(gB0, Bs[0] + w * 512);
    __syncthreads();

    f32x4 acc[4][2] = {};
    int cur = 0;
    for (int kk = 0; kk < K; kk += 32, cur ^= 1) {
        if (kk + 32 < K) {               // stage next tile while computing cur
            gld16(gA0 + kk + 32, As[cur ^ 1] + w * 512);
            gld16(gA1 + kk + 32, As[cur ^ 1] + (w + 4) * 512);
            gld16(gB0 + kk + 32, Bs[cur ^ 1] + w * 512);
        }
        bf16x8 a[4], b[2];
#pragma unroll
        for (int i = 0; i < 4; ++i)
            a[i] = *reinterpret_cast<const bf16x8*>(&As[cur][(wm + i * 16 + l15) * 32 + lhi * 8]);
#pragma unroll
        for (int j = 0; j < 2; ++j)
            b[j] = *reinterpret_cast<const bf16x8*>(&Bs[cur][(wn + j * 16 + l15) * 32 + lhi * 8]);
#pragma unroll
        for (int i = 0; i < 4; ++i)
#pragma unroll
            for (int j = 0; j < 2; ++j)
                acc[i][j] = __builtin_amdgcn_mfma_f32_16x16x32_bf16(a[i], b[j], acc[i][j], 0, 0, 0);
        __syncthreads();                 // drains prefetch + guards buffer reuse
    }
    const float sc = (nb < scaleNlim) ? scale : 1.0f;
#pragma unroll
    for (int i = 0; i < 4; ++i)
#pragma unroll
        for (int j = 0; j < 2; ++j)
#pragma unroll
            for (int r = 0; r < 4; ++r)
                C[(size_t)(mb + wm + i * 16 + lhi * 4 + r) * N + nb + wn + j * 16 + l15] =
                    (OutT)(acc[i][j][r] * sc);
}

// ---------------- Flash attention: gld16-staged K/V^T, swapped QK^T ---------
// Grid 512: block = (pair p, head h) does q-tiles p and 31-p (64 rows, 4 waves
// x 16 rows) -> 33 kv-iters/block. K and V^T staged via global_load_lds with
// both-sides XOR swizzle (linear dest, inv-swz source, swz read; <=2-way).
__global__ __launch_bounds__(256) void attn_kernel(const __bf16* __restrict__ QKV,
                                                   const __bf16* __restrict__ VT,
                                                   __bf16* __restrict__ Y) {
    const int bx = blockIdx.x;
    const int p = bx >> 5;         // 0..15
    const int h = bx & 31;
    const int kvh = h >> 2;
    const int tid = threadIdx.x;
    const int lane = tid & 63;
    const int w = tid >> 6;
    const int l15 = lane & 15, lhi = lane >> 4;

    __shared__ __align__(16) __bf16 Kl[2][64 * 64];   // K[kv][d], d-slot XOR-swz
    __shared__ __align__(16) __bf16 Vl[2][64 * 64];   // V^T[d][kv], kv-slot XOR-swz
    __shared__ __align__(16) __bf16 Pl[4][16][72];

    const __bf16* Qp = QKV + h * HD;
    const __bf16* Kp = QKV + KOFF + kvh * HD;
    const __bf16* Vth = VT + (size_t)(kvh * HD) * SEQ;

    // staging lane map: row-in-chunk sr = lane>>3, swizzled 16B slot (l&7)^sr
    const int sr = lane >> 3;
    const int sc8 = ((lane & 7) ^ sr) * 8;      // source col elems (pre-swizzled)
    const int rswz = (l15 & 7);                 // read-side XOR key (row&7)

    for (int seg = 0; seg < 2; ++seg) {
        const int qt = seg ? (31 - p) : p;
        const int qb = qt * 64;
        const int mtile = qt;                  // inclusive kv-tile bound
        const int qrow = qb + w * 16 + l15;    // this lane's q (swapped layout)

        const __bf16* qptr = Qp + (size_t)qrow * QKVD;
        bf16x8 qf0 = *reinterpret_cast<const bf16x8*>(qptr + lhi * 8);
        bf16x8 qf1 = *reinterpret_cast<const bf16x8*>(qptr + 32 + lhi * 8);

        f32x4 o[4] = {};
        float mrun = -1e30f;
        float lpart = 0.f;

        // prologue: stage kv tile 0 into buffer 0 (4 gld16 per wave)
#pragma unroll
        for (int c = 0; c < 2; ++c) {
            const int row = w * 16 + c * 8;
            gld16(Kp + (size_t)(row + sr) * QKVD + sc8, &Kl[0][row * 64]);
            gld16(Vth + (size_t)(row + sr) * SEQ + sc8, &Vl[0][row * 64]);
        }
        __syncthreads();

        int cur = 0;
        for (int j = 0; j <= mtile; ++j, cur ^= 1) {
            // stage tile j+1 into the other buffer (async, drains at barrier)
            const bool pre = (j < mtile);
            if (pre) {
                const int nxt = cur ^ 1;
#pragma unroll
                for (int c = 0; c < 2; ++c) {
                    const int row = w * 16 + c * 8;
                    gld16(Kp + (size_t)((j + 1) * 64 + row + sr) * QKVD + sc8,
                          &Kl[nxt][row * 64]);
                    gld16(Vth + (size_t)(row + sr) * SEQ + (j + 1) * 64 + sc8,
                          &Vl[nxt][row * 64]);
                }
            }

            // S^T = K Q^T (swapped): lane owns q=l15; kv = t*16 + lhi*4 + r
            f32x4 sacc[4];
            __builtin_amdgcn_s_setprio(1);
#pragma unroll
            for (int t = 0; t < 4; ++t) {
                const int rb = (t * 16 + l15) * 64;
                bf16x8 kf0 = *reinterpret_cast<const bf16x8*>(
                    &Kl[cur][rb + ((lhi ^ rswz) * 8)]);
                bf16x8 kf1 = *reinterpret_cast<const bf16x8*>(
                    &Kl[cur][rb + (((4 + lhi) ^ rswz) * 8)]);
                f32x4 z = {0.f, 0.f, 0.f, 0.f};
                z = __builtin_amdgcn_mfma_f32_16x16x32_bf16(kf0, qf0, z, 0, 0, 0);
                z = __builtin_amdgcn_mfma_f32_16x16x32_bf16(kf1, qf1, z, 0, 0, 0);
                sacc[t] = z;
            }
            __builtin_amdgcn_s_setprio(0);

            // causal mask: only the diagonal tile needs it
            if (j == mtile) {
#pragma unroll
                for (int t = 0; t < 4; ++t)
#pragma unroll
                    for (int r = 0; r < 4; ++r) {
                        const int kv = j * 64 + t * 16 + lhi * 4 + r;
                        if (kv > qrow) sacc[t][r] = -1e30f;
                    }
            }

            // per-lane partial max; cross-lane only on (rare) rescale
            float mt[4];
#pragma unroll
            for (int t = 0; t < 4; ++t)
                mt[t] = fmaxf(fmaxf(sacc[t][0], sacc[t][1]),
                              fmaxf(sacc[t][2], sacc[t][3]));
            const float pm = fmaxf(fmaxf(mt[0], mt[1]), fmaxf(mt[2], mt[3]));

            if (!__all(pm - mrun <= 8.0f)) {           // T13 defer-max
                float full = pm;
                full = fmaxf(full, __shfl_xor(full, 16));
                full = fmaxf(full, __shfl_xor(full, 32));
                const float mn = fmaxf(mrun, full);
                const float a = exp2f(mrun - mn);
                mrun = mn;
                lpart *= a;
                float ar[4];
#pragma unroll
                for (int r = 0; r < 4; ++r) ar[r] = __shfl(a, lhi * 4 + r);
#pragma unroll
                for (int t = 0; t < 4; ++t)
#pragma unroll
                    for (int r = 0; r < 4; ++r) o[t][r] *= ar[r];
            }

            // P = exp2(S - m), partial sum, pack to LDS
#pragma unroll
            for (int t = 0; t < 4; ++t) {
                bf16x4 pk;
#pragma unroll
                for (int r = 0; r < 4; ++r) {
                    const float pv = exp2f(sacc[t][r] - mrun);
                    lpart += pv;
                    pk[r] = (__bf16)pv;
                }
                *reinterpret_cast<bf16x4*>(&Pl[w][l15][t * 16 + lhi * 4]) = pk;
            }

            // O += P V
            bf16x8 pf0 = *reinterpret_cast<const bf16x8*>(&Pl[w][l15][lhi * 8]);
            bf16x8 pf1 = *reinterpret_cast<const bf16x8*>(&Pl[w][l15][32 + lhi * 8]);
            __builtin_amdgcn_s_setprio(1);
#pragma unroll
            for (int t = 0; t < 4; ++t) {
                const int rb = (t * 16 + l15) * 64;
                bf16x8 vf0 = *reinterpret_cast<const bf16x8*>(
                    &Vl[cur][rb + ((lhi ^ rswz) * 8)]);
                bf16x8 vf1 = *reinterpret_cast<const bf16x8*>(
                    &Vl[cur][rb + (((4 + lhi) ^ rswz) * 8)]);
                o[t] = __builtin_amdgcn_mfma_f32_16x16x32_bf16(pf0, vf0, o[t], 0, 0, 0);
                o[t] = __builtin_amdgcn_mfma_f32_16x16x32_bf16(pf1, vf1, o[t], 0, 0, 0);
            }
            __builtin_amdgcn_s_setprio(0);

            __syncthreads();   // drains gld16 prefetch + guards buffer reuse
        }

        // epilogue: combine partial sums, divide, store
        float ls = lpart;
        ls += __shfl_xor(ls, 16);
        ls += __shfl_xor(ls, 32);
        float lr[4];
#pragma unroll
        for (int r = 0; r < 4; ++r) lr[r] = __shfl(ls, lhi * 4 + r);
#pragma unroll
        for (int t = 0; t < 4; ++t)
#pragma unroll
            for (int r = 0; r < 4; ++r) {
                const float val = o[t][r] / lr[r];
                Y[(size_t)(qb + w * 16 + lhi * 4 + r) * DIM + h * HD + t * 16 + l15] =
                    (__bf16)val;
            }
    }
}

extern "C" void kernel_launch(void* const* d_in, const int* in_sizes, int n_in,
                              void* d_out, int out_size, void* d_ws, size_t ws_size,
                              hipStream_t stream) {
    const float* x    = (const float*)d_in[0];
    const float* fcos = (const float*)d_in[1];
    const float* fsin = (const float*)d_in[2];
    const float* wq   = (const float*)d_in[3];
    const float* wk   = (const float*)d_in[4];
    const float* wv   = (const float*)d_in[5];
    const float* wo   = (const float*)d_in[6];
    float* out = (float*)d_out;

    __bf16* xb    = (__bf16*)d_ws;                       // [2048][2048]
    __bf16* wqkvb = xb + (size_t)SEQ * DIM;              // [3072][2048]
    __bf16* wob   = wqkvb + (size_t)QKVD * DIM;          // [2048][2048]
    __bf16* QKVb  = wob + (size_t)DIM * DIM;             // [2048][3072]
    __bf16* Yb    = QKVb + (size_t)SEQ * QKVD;           // [2048][2048]
    __bf16* VTb   = Yb + (size_t)SEQ * DIM;              // [512][2048]

    const int nx  = SEQ * DIM / 4;
    const int nw  = DIM * DIM / 4;
    const int nkv = KVDIM * DIM / 4;
    cvt_f32_bf16<<<(nx + 255) / 256, 256, 0, stream>>>(x, xb, nx);
    cvt_f32_bf16<<<(nw + 255) / 256, 256, 0, stream>>>(wq, wqkvb, nw);
    cvt_f32_bf16<<<(nkv + 255) / 256, 256, 0, stream>>>(wk, wqkvb + (size_t)KOFF * DIM, nkv);
    cvt_f32_bf16<<<(nkv + 255) / 256, 256, 0, stream>>>(wv, wqkvb + (size_t)VOFF * DIM, nkv);
    cvt_f32_bf16<<<(nw + 255) / 256, 256, 0, stream>>>(wo, wob, nw);

    // fused QKV projection; Q pre-scaled by (1/sqrt(64)) * log2(e) (exp2 softmax)
    gemm_tn<__bf16><<<dim3(QKVD / 64, SEQ / 128), 256, 0, stream>>>(
        xb, wqkvb, QKVb, SEQ, QKVD, DIM, 0.125f * 1.4426950408889634f, KOFF);

    rope_kernel<<<dim3((DIM / 2) / 256, SEQ), 256, 0, stream>>>(QKVb, fcos, fsin, QKVD);
    rope_kernel<<<dim3((KVDIM / 2) / 256, SEQ), 256, 0, stream>>>(QKVb + KOFF, fcos, fsin, QKVD);

    transpose_v<<<dim3(SEQ / 64, KVDIM / 64), 256, 0, stream>>>(QKVb + VOFF, VTb);

    attn_kernel<<<dim3(512), 256, 0, stream>>>(QKVb, VTb, Yb);

    gemm_tn<float><<<dim3(DIM / 64, SEQ / 128), 256, 0, stream>>>(
        Yb, wob, out, SEQ, DIM, DIM, 1.0f, 0);
}

// Round 8
// 150.997 us; speedup vs baseline: 2.9070x; 1.1305x over previous
//
#include <hip/hip_runtime.h>
#include <hip/hip_bf16.h>

typedef __attribute__((ext_vector_type(8))) __bf16 bf16x8;
typedef __attribute__((ext_vector_type(4))) __bf16 bf16x4;
typedef __attribute__((ext_vector_type(4))) float f32x4;

#define DIM 2048
#define SEQ 2048
#define NH 32
#define NKV 8
#define HD 64
#define QKVD 3072          // 2048 Q | 512 K | 512 V packed columns
#define KOFF 2048
#define VOFF 2560
#define KVDIM 512

// async global->LDS, 16B per lane, wave-uniform LDS base (HW: base + lane*16)
__device__ __forceinline__ void gld16(const __bf16* g, __bf16* l) {
    __builtin_amdgcn_global_load_lds(
        (const __attribute__((address_space(1))) void*)g,
        (__attribute__((address_space(3))) void*)l, 16, 0, 0);
}

// ---------------- fp32 -> bf16 convert (vectorized) ----------------
__global__ void cvt_f32_bf16(const float* __restrict__ in, __bf16* __restrict__ out, int n4) {
    int i = blockIdx.x * blockDim.x + threadIdx.x;
    if (i < n4) {
        float4 v = reinterpret_cast<const float4*>(in)[i];
        bf16x4 o;
        o[0] = (__bf16)v.x; o[1] = (__bf16)v.y; o[2] = (__bf16)v.z; o[3] = (__bf16)v.w;
        reinterpret_cast<bf16x4*>(out)[i] = o;
    }
}

// ---------------- V transpose: V[seq][512] -> VT[512][seq] (one-shot) -------
__global__ __launch_bounds__(256) void transpose_v(const __bf16* __restrict__ V,
                                                   __bf16* __restrict__ VT) {
    __shared__ __bf16 t[64][72];
    const int tid = threadIdx.x;
    const int r = tid >> 2, c0 = (tid & 3) * 16;
    const int sb = blockIdx.x * 64;   // seq base
    const int db = blockIdx.y * 64;   // d base
    bf16x8 a0 = *reinterpret_cast<const bf16x8*>(V + (size_t)(sb + r) * QKVD + db + c0);
    bf16x8 a1 = *reinterpret_cast<const bf16x8*>(V + (size_t)(sb + r) * QKVD + db + c0 + 8);
#pragma unroll
    for (int e = 0; e < 8; ++e) { t[c0 + e][r] = a0[e]; t[c0 + 8 + e][r] = a1[e]; }
    __syncthreads();
    bf16x8 o0 = *reinterpret_cast<const bf16x8*>(&t[r][c0]);
    bf16x8 o1 = *reinterpret_cast<const bf16x8*>(&t[r][c0 + 8]);
    *reinterpret_cast<bf16x8*>(VT + (size_t)(db + r) * SEQ + sb + c0) = o0;
    *reinterpret_cast<bf16x8*>(VT + (size_t)(db + r) * SEQ + sb + c0 + 8) = o1;
}

// ---------------- TN GEMM: 128x64 tile, BK=64 (2 x 32-k subtiles/barrier) ----
// dbuf, prefetch-next, 1 barrier per 64-K. Optional fused RoPE epilogue
// (cols < VOFF get rotated; pair partner via shfl_xor(v,1)).
template <typename OutT, bool ROPE>
__global__ __launch_bounds__(256) void gemm_tn(const __bf16* __restrict__ A,
                                               const __bf16* __restrict__ B,
                                               OutT* __restrict__ C,
                                               int M, int N, int K,
                                               float scale, int scaleNlim,
                                               const float* __restrict__ fc,
                                               const float* __restrict__ fs) {
    __shared__ __align__(16) __bf16 As[2][2][128 * 32];
    __shared__ __align__(16) __bf16 Bs[2][2][64 * 32];
    const int tid = threadIdx.x;
    const int lane = tid & 63;
    const int w = tid >> 6;
    const int l15 = lane & 15, lhi = lane >> 4;
    const int mb = blockIdx.y * 128;
    const int nb = blockIdx.x * 64;
    const int wm = (w >> 1) * 64, wn = (w & 1) * 32;

    const int srow = lane >> 2, scol = (lane & 3) * 8;
    const __bf16* gA0 = A + (size_t)(mb + w * 16 + srow) * K + scol;
    const __bf16* gA1 = A + (size_t)(mb + (w + 4) * 16 + srow) * K + scol;
    const __bf16* gB0 = B + (size_t)(nb + w * 16 + srow) * K + scol;

    auto stage = [&](int kk, int buf) {
#pragma unroll
        for (int s = 0; s < 2; ++s) {
            gld16(gA0 + kk + s * 32, As[buf][s] + w * 512);
            gld16(gA1 + kk + s * 32, As[buf][s] + (w + 4) * 512);
            gld16(gB0 + kk + s * 32, Bs[buf][s] + w * 512);
        }
    };

    stage(0, 0);
    __syncthreads();

    f32x4 acc[4][2] = {};
    int cur = 0;
    for (int kk = 0; kk < K; kk += 64, cur ^= 1) {
        if (kk + 64 < K) stage(kk + 64, cur ^ 1);
#pragma unroll
        for (int s = 0; s < 2; ++s) {
            bf16x8 a[4], b[2];
#pragma unroll
            for (int i = 0; i < 4; ++i)
                a[i] = *reinterpret_cast<const bf16x8*>(&As[cur][s][(wm + i * 16 + l15) * 32 + lhi * 8]);
#pragma unroll
            for (int j = 0; j < 2; ++j)
                b[j] = *reinterpret_cast<const bf16x8*>(&Bs[cur][s][(wn + j * 16 + l15) * 32 + lhi * 8]);
#pragma unroll
            for (int i = 0; i < 4; ++i)
#pragma unroll
                for (int j = 0; j < 2; ++j)
                    acc[i][j] = __builtin_amdgcn_mfma_f32_16x16x32_bf16(a[i], b[j], acc[i][j], 0, 0, 0);
        }
        __syncthreads();                 // drains prefetch + guards buffer reuse
    }

    const float sc = (nb < scaleNlim) ? scale : 1.0f;
    const bool doRope = ROPE && (nb < VOFF);   // block-uniform (64-col tiles)
#pragma unroll
    for (int i = 0; i < 4; ++i)
#pragma unroll
        for (int j = 0; j < 2; ++j)
#pragma unroll
            for (int r = 0; r < 4; ++r) {
                float v = acc[i][j][r] * sc;
                if (doRope) {
                    const int col = nb + wn + j * 16 + l15;
                    const int row = mb + wm + i * 16 + lhi * 4 + r;
                    const float vp = __shfl_xor(v, 1);
                    const int fi = (col & 63) >> 1;
                    const float cc = fc[row * 32 + fi];
                    const float ss = fs[row * 32 + fi];
                    v = (col & 1) ? (vp * ss + v * cc) : (v * cc - vp * ss);
                }
                C[(size_t)(mb + wm + i * 16 + lhi * 4 + r) * N + nb + wn + j * 16 + l15] = (OutT)v;
            }
}

// ---------------- Flash attention: KVBLK=128, swapped QK^T ------------------
// Grid 512: block = (pair p, head h) does q-tiles p and 31-p (64 rows, 4 waves
// x 16 rows) -> 17 kv-128-iterations per block (balanced for all p).
// K [128][64] and V^T [64][128] staged via gld16 with both-sides XOR swizzle;
// P via wave-private LDS [16][128], 8B-slot XOR swizzle.
__global__ __launch_bounds__(256) void attn_kernel(const __bf16* __restrict__ QKV,
                                                   const __bf16* __restrict__ VT,
                                                   __bf16* __restrict__ Y) {
    const int bx = blockIdx.x;
    const int p = bx >> 5;         // 0..15
    const int h = bx & 31;
    const int kvh = h >> 2;
    const int tid = threadIdx.x;
    const int lane = tid & 63;
    const int w = tid >> 6;
    const int l15 = lane & 15, lhi = lane >> 4;

    __shared__ __align__(16) __bf16 Kl[2][128 * 64];   // 32 KB
    __shared__ __align__(16) __bf16 Vl[2][64 * 128];   // 32 KB
    __shared__ __align__(16) __bf16 Pl[4][16 * 128];   // 16 KB  (total 80 KB)

    const __bf16* Qp = QKV + h * HD;
    const __bf16* Kp = QKV + KOFF + kvh * HD;
    const __bf16* Vth = VT + (size_t)(kvh * HD) * SEQ;

    // K staging map: 1KB chunk = 8 rows x 64; lane -> row l>>3, slot l&7
    const int ksr = lane >> 3;
    const int ksc = ((lane & 7) ^ ksr) * 8;            // pre-swizzled src col
    // V staging map: 1KB chunk = 4 rows x 128; lane -> row l>>4, slot l&15
    const int vsr = lane >> 4;

    auto stage = [&](int jt, int buf) {
        const int kvb = jt * 128;
#pragma unroll
        for (int c = 0; c < 4; ++c) {                   // K: rows [w*32, w*32+32)
            const int rb = w * 32 + c * 8;
            gld16(Kp + (size_t)(kvb + rb + ksr) * QKVD + ksc, &Kl[buf][rb * 64]);
        }
#pragma unroll
        for (int c = 0; c < 4; ++c) {                   // V^T: d-rows [w*16, w*16+16)
            const int db = w * 16 + c * 4;
            const int row = db + vsr;
            const int col = ((lane & 15) ^ (row & 7)) * 8;
            gld16(Vth + (size_t)row * SEQ + kvb + col, &Vl[buf][db * 128]);
        }
    };

    const int pkey = (l15 & 7) << 2;                    // Pl 8B-slot XOR key

    for (int seg = 0; seg < 2; ++seg) {
        const int qt = seg ? (31 - p) : p;
        const int qb = qt * 64;
        const int nkt = (qt + 2) >> 1;                  // ceil((qt+1)*64 / 128)
        const int qrow = qb + w * 16 + l15;             // lane's q (swapped layout)

        const __bf16* qptr = Qp + (size_t)qrow * QKVD;
        bf16x8 qf0 = *reinterpret_cast<const bf16x8*>(qptr + lhi * 8);
        bf16x8 qf1 = *reinterpret_cast<const bf16x8*>(qptr + 32 + lhi * 8);

        f32x4 o[4] = {};
        float mrun = -1e30f;
        float lpart = 0.f;

        stage(0, 0);
        __syncthreads();

        int cur = 0;
        for (int j = 0; j < nkt; ++j, cur ^= 1) {
            const bool pre = (j + 1 < nkt);
            if (pre) stage(j + 1, cur ^ 1);

            // S^T = K Q^T: lane owns q=l15; kv = t*16 + lhi*4 + r, t=0..7
            f32x4 sacc[8];
            __builtin_amdgcn_s_setprio(1);
#pragma unroll
            for (int t = 0; t < 8; ++t) {
                const int row = t * 16 + l15;
                const int key = row & 7;
                bf16x8 kf0 = *reinterpret_cast<const bf16x8*>(
                    &Kl[cur][row * 64 + ((lhi ^ key) * 8)]);
                bf16x8 kf1 = *reinterpret_cast<const bf16x8*>(
                    &Kl[cur][row * 64 + (((4 + lhi) ^ key) * 8)]);
                f32x4 z = {0.f, 0.f, 0.f, 0.f};
                z = __builtin_amdgcn_mfma_f32_16x16x32_bf16(kf0, qf0, z, 0, 0, 0);
                z = __builtin_amdgcn_mfma_f32_16x16x32_bf16(kf1, qf1, z, 0, 0, 0);
                sacc[t] = z;
            }
            __builtin_amdgcn_s_setprio(0);

            // causal mask: last tile only (covers the invalid upper half too)
            if (j == nkt - 1) {
#pragma unroll
                for (int t = 0; t < 8; ++t)
#pragma unroll
                    for (int r = 0; r < 4; ++r) {
                        const int kv = j * 128 + t * 16 + lhi * 4 + r;
                        if (kv > qrow) sacc[t][r] = -1e30f;
                    }
            }

            // per-lane partial max; cross-lane only on (rare) rescale
            float mt[8];
#pragma unroll
            for (int t = 0; t < 8; ++t)
                mt[t] = fmaxf(fmaxf(sacc[t][0], sacc[t][1]),
                              fmaxf(sacc[t][2], sacc[t][3]));
            float pm = fmaxf(fmaxf(fmaxf(mt[0], mt[1]), fmaxf(mt[2], mt[3])),
                             fmaxf(fmaxf(mt[4], mt[5]), fmaxf(mt[6], mt[7])));

            if (!__all(pm - mrun <= 8.0f)) {           // T13 defer-max
                float full = pm;
                full = fmaxf(full, __shfl_xor(full, 16));
                full = fmaxf(full, __shfl_xor(full, 32));
                const float mn = fmaxf(mrun, full);
                const float a = exp2f(mrun - mn);
                mrun = mn;
                lpart *= a;
                float ar[4];
#pragma unroll
                for (int r = 0; r < 4; ++r) ar[r] = __shfl(a, lhi * 4 + r);
#pragma unroll
                for (int t = 0; t < 4; ++t)
#pragma unroll
                    for (int r = 0; r < 4; ++r) o[t][r] *= ar[r];
            }

            // P = exp2(S - m), partial sum, pack to swizzled Pl
#pragma unroll
            for (int t = 0; t < 8; ++t) {
                bf16x4 pk;
#pragma unroll
                for (int r = 0; r < 4; ++r) {
                    const float pv = exp2f(sacc[t][r] - mrun);
                    lpart += pv;
                    pk[r] = (__bf16)pv;
                }
                const int sw = (t * 4 + lhi) ^ pkey;    // 8B slot, swizzled
                *reinterpret_cast<bf16x4*>(&Pl[w][l15 * 128 + sw * 4]) = pk;
            }

            // O += P V   (pf[c] covers kv c*32..c*32+31)
            bf16x8 pf[4];
#pragma unroll
            for (int c = 0; c < 4; ++c) {
                const int s0 = (c * 8 + lhi * 2) ^ pkey;
                pf[c] = *reinterpret_cast<const bf16x8*>(&Pl[w][l15 * 128 + s0 * 4]);
            }
            __builtin_amdgcn_s_setprio(1);
#pragma unroll
            for (int t = 0; t < 4; ++t) {
                const int row = t * 16 + l15;           // d-row of V^T
                const int key = row & 7;
#pragma unroll
                for (int c = 0; c < 4; ++c) {
                    bf16x8 vf = *reinterpret_cast<const bf16x8*>(
                        &Vl[cur][row * 128 + (((c * 4 + lhi) ^ key) * 8)]);
                    o[t] = __builtin_amdgcn_mfma_f32_16x16x32_bf16(pf[c], vf, o[t], 0, 0, 0);
                }
            }
            __builtin_amdgcn_s_setprio(0);

            __syncthreads();   // drains gld16 prefetch + guards buffer reuse
        }

        // epilogue: combine partial sums, divide, store
        float ls = lpart;
        ls += __shfl_xor(ls, 16);
        ls += __shfl_xor(ls, 32);
        float lr[4];
#pragma unroll
        for (int r = 0; r < 4; ++r) lr[r] = __shfl(ls, lhi * 4 + r);
#pragma unroll
        for (int t = 0; t < 4; ++t)
#pragma unroll
            for (int r = 0; r < 4; ++r) {
                const float val = o[t][r] / lr[r];
                Y[(size_t)(qb + w * 16 + lhi * 4 + r) * DIM + h * HD + t * 16 + l15] =
                    (__bf16)val;
            }
    }
}

extern "C" void kernel_launch(void* const* d_in, const int* in_sizes, int n_in,
                              void* d_out, int out_size, void* d_ws, size_t ws_size,
                              hipStream_t stream) {
    const float* x    = (const float*)d_in[0];
    const float* fcos = (const float*)d_in[1];
    const float* fsin = (const float*)d_in[2];
    const float* wq   = (const float*)d_in[3];
    const float* wk   = (const float*)d_in[4];
    const float* wv   = (const float*)d_in[5];
    const float* wo   = (const float*)d_in[6];
    float* out = (float*)d_out;

    __bf16* xb    = (__bf16*)d_ws;                       // [2048][2048]
    __bf16* wqkvb = xb + (size_t)SEQ * DIM;              // [3072][2048]
    __bf16* wob   = wqkvb + (size_t)QKVD * DIM;          // [2048][2048]
    __bf16* QKVb  = wob + (size_t)DIM * DIM;             // [2048][3072]
    __bf16* Yb    = QKVb + (size_t)SEQ * QKVD;           // [2048][2048]
    __bf16* VTb   = Yb + (size_t)SEQ * DIM;              // [512][2048]

    const int nx  = SEQ * DIM / 4;
    const int nw  = DIM * DIM / 4;
    const int nkv = KVDIM * DIM / 4;
    cvt_f32_bf16<<<(nx + 255) / 256, 256, 0, stream>>>(x, xb, nx);
    cvt_f32_bf16<<<(nw + 255) / 256, 256, 0, stream>>>(wq, wqkvb, nw);
    cvt_f32_bf16<<<(nkv + 255) / 256, 256, 0, stream>>>(wk, wqkvb + (size_t)KOFF * DIM, nkv);
    cvt_f32_bf16<<<(nkv + 255) / 256, 256, 0, stream>>>(wv, wqkvb + (size_t)VOFF * DIM, nkv);
    cvt_f32_bf16<<<(nw + 255) / 256, 256, 0, stream>>>(wo, wob, nw);

    // fused QKV projection + RoPE epilogue; Q pre-scaled by 0.125*log2(e)
    gemm_tn<__bf16, true><<<dim3(QKVD / 64, SEQ / 128), 256, 0, stream>>>(
        xb, wqkvb, QKVb, SEQ, QKVD, DIM, 0.125f * 1.4426950408889634f, KOFF, fcos, fsin);

    transpose_v<<<dim3(SEQ / 64, KVDIM / 64), 256, 0, stream>>>(QKVb + VOFF, VTb);

    attn_kernel<<<dim3(512), 256, 0, stream>>>(QKVb, VTb, Yb);

    gemm_tn<float, false><<<dim3(DIM / 64, SEQ / 128), 256, 0, stream>>>(
        Yb, wob, out, SEQ, DIM, DIM, 1.0f, 0, nullptr, nullptr);
}

// Round 9
// 145.750 us; speedup vs baseline: 3.0116x; 1.0360x over previous
//
#include <hip/hip_runtime.h>
#include <hip/hip_bf16.h>

typedef __attribute__((ext_vector_type(8))) __bf16 bf16x8;
typedef __attribute__((ext_vector_type(4))) __bf16 bf16x4;
typedef __attribute__((ext_vector_type(4))) float f32x4;

#define DIM 2048
#define SEQ 2048
#define NH 32
#define NKV 8
#define HD 64
#define QKVD 3072          // 2048 Q | 512 K | 512 V packed columns
#define KOFF 2048
#define VOFF 2560
#define KVDIM 512

// async global->LDS, 16B per lane, wave-uniform LDS base (HW: base + lane*16)
__device__ __forceinline__ void gld16(const __bf16* g, __bf16* l) {
    __builtin_amdgcn_global_load_lds(
        (const __attribute__((address_space(1))) void*)g,
        (__attribute__((address_space(3))) void*)l, 16, 0, 0);
}

// ---------------- fp32 -> bf16 convert (vectorized) ----------------
__global__ void cvt_f32_bf16(const float* __restrict__ in, __bf16* __restrict__ out, int n4) {
    int i = blockIdx.x * blockDim.x + threadIdx.x;
    if (i < n4) {
        float4 v = reinterpret_cast<const float4*>(in)[i];
        bf16x4 o;
        o[0] = (__bf16)v.x; o[1] = (__bf16)v.y; o[2] = (__bf16)v.z; o[3] = (__bf16)v.w;
        reinterpret_cast<bf16x4*>(out)[i] = o;
    }
}

// ---------------- V transpose: V[seq][512] -> VT[512][seq] (one-shot) -------
__global__ __launch_bounds__(256) void transpose_v(const __bf16* __restrict__ V,
                                                   __bf16* __restrict__ VT) {
    __shared__ __bf16 t[64][72];
    const int tid = threadIdx.x;
    const int r = tid >> 2, c0 = (tid & 3) * 16;
    const int sb = blockIdx.x * 64;   // seq base
    const int db = blockIdx.y * 64;   // d base
    bf16x8 a0 = *reinterpret_cast<const bf16x8*>(V + (size_t)(sb + r) * QKVD + db + c0);
    bf16x8 a1 = *reinterpret_cast<const bf16x8*>(V + (size_t)(sb + r) * QKVD + db + c0 + 8);
#pragma unroll
    for (int e = 0; e < 8; ++e) { t[c0 + e][r] = a0[e]; t[c0 + 8 + e][r] = a1[e]; }
    __syncthreads();
    bf16x8 o0 = *reinterpret_cast<const bf16x8*>(&t[r][c0]);
    bf16x8 o1 = *reinterpret_cast<const bf16x8*>(&t[r][c0 + 8]);
    *reinterpret_cast<bf16x8*>(VT + (size_t)(db + r) * SEQ + sb + c0) = o0;
    *reinterpret_cast<bf16x8*>(VT + (size_t)(db + r) * SEQ + sb + c0 + 8) = o1;
}

// ---------------- TN GEMM: 128x64 tile, BK=64 (2 x 32-k subtiles/barrier) ----
// dbuf, prefetch-next, 1 barrier per 64-K. Optional fused RoPE epilogue.
template <typename OutT, bool ROPE>
__global__ __launch_bounds__(256) void gemm_tn(const __bf16* __restrict__ A,
                                               const __bf16* __restrict__ B,
                                               OutT* __restrict__ C,
                                               int M, int N, int K,
                                               float scale, int scaleNlim,
                                               const float* __restrict__ fc,
                                               const float* __restrict__ fs) {
    __shared__ __align__(16) __bf16 As[2][2][128 * 32];
    __shared__ __align__(16) __bf16 Bs[2][2][64 * 32];
    const int tid = threadIdx.x;
    const int lane = tid & 63;
    const int w = tid >> 6;
    const int l15 = lane & 15, lhi = lane >> 4;
    const int mb = blockIdx.y * 128;
    const int nb = blockIdx.x * 64;
    const int wm = (w >> 1) * 64, wn = (w & 1) * 32;

    const int srow = lane >> 2, scol = (lane & 3) * 8;
    const __bf16* gA0 = A + (size_t)(mb + w * 16 + srow) * K + scol;
    const __bf16* gA1 = A + (size_t)(mb + (w + 4) * 16 + srow) * K + scol;
    const __bf16* gB0 = B + (size_t)(nb + w * 16 + srow) * K + scol;

    auto stage = [&](int kk, int buf) {
#pragma unroll
        for (int s = 0; s < 2; ++s) {
            gld16(gA0 + kk + s * 32, As[buf][s] + w * 512);
            gld16(gA1 + kk + s * 32, As[buf][s] + (w + 4) * 512);
            gld16(gB0 + kk + s * 32, Bs[buf][s] + w * 512);
        }
    };

    stage(0, 0);
    __syncthreads();

    f32x4 acc[4][2] = {};
    int cur = 0;
    for (int kk = 0; kk < K; kk += 64, cur ^= 1) {
        if (kk + 64 < K) stage(kk + 64, cur ^ 1);
#pragma unroll
        for (int s = 0; s < 2; ++s) {
            bf16x8 a[4], b[2];
#pragma unroll
            for (int i = 0; i < 4; ++i)
                a[i] = *reinterpret_cast<const bf16x8*>(&As[cur][s][(wm + i * 16 + l15) * 32 + lhi * 8]);
#pragma unroll
            for (int j = 0; j < 2; ++j)
                b[j] = *reinterpret_cast<const bf16x8*>(&Bs[cur][s][(wn + j * 16 + l15) * 32 + lhi * 8]);
#pragma unroll
            for (int i = 0; i < 4; ++i)
#pragma unroll
                for (int j = 0; j < 2; ++j)
                    acc[i][j] = __builtin_amdgcn_mfma_f32_16x16x32_bf16(a[i], b[j], acc[i][j], 0, 0, 0);
        }
        __syncthreads();                 // drains prefetch + guards buffer reuse
    }

    const float sc = (nb < scaleNlim) ? scale : 1.0f;
    const bool doRope = ROPE && (nb < VOFF);   // block-uniform (64-col tiles)
#pragma unroll
    for (int i = 0; i < 4; ++i)
#pragma unroll
        for (int j = 0; j < 2; ++j)
#pragma unroll
            for (int r = 0; r < 4; ++r) {
                float v = acc[i][j][r] * sc;
                if (doRope) {
                    const int col = nb + wn + j * 16 + l15;
                    const int row = mb + wm + i * 16 + lhi * 4 + r;
                    const float vp = __shfl_xor(v, 1);
                    const int fi = (col & 63) >> 1;
                    const float cc = fc[row * 32 + fi];
                    const float ss = fs[row * 32 + fi];
                    v = (col & 1) ? (vp * ss + v * cc) : (v * cc - vp * ss);
                }
                C[(size_t)(mb + wm + i * 16 + lhi * 4 + r) * N + nb + wn + j * 16 + l15] = (OutT)v;
            }
}

// ---------------- Flash attention: 4-blocks/CU all-resident -----------------
// Grid 1024: block = one 64-row q-tile (4 waves x 16 rows), KVBLK=64, dbuf.
// LDS = exactly 40960 B -> 4 blocks/CU. qt chosen so the 4 blocks sharing a
// CU (stride-256 co-residency under XCD round-robin) sum to 62 kv-iters.
__global__ __launch_bounds__(256, 4) void attn_kernel(const __bf16* __restrict__ QKV,
                                                      const __bf16* __restrict__ VT,
                                                      __bf16* __restrict__ Y) {
    const int bx = blockIdx.x;
    const int g = bx >> 8;                // 0..3
    const int a = (bx >> 5) & 7;          // 0..7
    const int h = bx & 31;
    const int qt = (g == 0) ? 31 - a : (g == 1) ? a : (g == 2) ? 23 - a : 8 + a;
    const int kvh = h >> 2;
    const int tid = threadIdx.x;
    const int lane = tid & 63;
    const int w = tid >> 6;
    const int l15 = lane & 15, lhi = lane >> 4;

    __shared__ __align__(16) __bf16 Kl[2][64 * 64];   // 16 KB, d-slot XOR-swz
    __shared__ __align__(16) __bf16 Vl[2][64 * 64];   // 16 KB, kv-slot XOR-swz
    __shared__ __align__(16) __bf16 Pl[4][16 * 64];   // 8 KB, 8B-slot XOR-swz

    const __bf16* Qp = QKV + h * HD;
    const __bf16* Kp = QKV + KOFF + kvh * HD;
    const __bf16* Vth = VT + (size_t)(kvh * HD) * SEQ;

    // staging lane map: row-in-chunk sr = lane>>3, swizzled 16B slot (l&7)^sr
    const int sr = lane >> 3;
    const int ksc = ((lane & 7) ^ sr) * 8;      // pre-swizzled source col
    const int rswz = (l15 & 7);                 // read-side XOR key (row&7)

    auto stage = [&](int jt, int buf) {
        const int kvb = jt * 64;
#pragma unroll
        for (int c = 0; c < 2; ++c) {
            const int row = w * 16 + c * 8;
            gld16(Kp + (size_t)(kvb + row + sr) * QKVD + ksc, &Kl[buf][row * 64]);
            gld16(Vth + (size_t)(row + sr) * SEQ + kvb + ksc, &Vl[buf][row * 64]);
        }
    };

    const int qb = qt * 64;
    const int qrow = qb + w * 16 + l15;    // this lane's q (swapped layout)

    const __bf16* qptr = Qp + (size_t)qrow * QKVD;
    bf16x8 qf0 = *reinterpret_cast<const bf16x8*>(qptr + lhi * 8);
    bf16x8 qf1 = *reinterpret_cast<const bf16x8*>(qptr + 32 + lhi * 8);

    f32x4 o[4] = {};
    float mrun = -1e30f;
    float lpart = 0.f;

    const int pkey = (l15 & 7) << 1;       // Pl 8B-slot XOR key (even)

    stage(0, 0);
    __syncthreads();

    int cur = 0;
    for (int j = 0; j <= qt; ++j, cur ^= 1) {
        const bool pre = (j < qt);
        if (pre) stage(j + 1, cur ^ 1);

        // S^T = K Q^T (swapped): lane owns q=l15; kv = t*16 + lhi*4 + r
        f32x4 sacc[4];
        __builtin_amdgcn_s_setprio(1);
#pragma unroll
        for (int t = 0; t < 4; ++t) {
            const int rb = (t * 16 + l15) * 64;
            bf16x8 kf0 = *reinterpret_cast<const bf16x8*>(
                &Kl[cur][rb + ((lhi ^ rswz) * 8)]);
            bf16x8 kf1 = *reinterpret_cast<const bf16x8*>(
                &Kl[cur][rb + (((4 + lhi) ^ rswz) * 8)]);
            f32x4 z = {0.f, 0.f, 0.f, 0.f};
            z = __builtin_amdgcn_mfma_f32_16x16x32_bf16(kf0, qf0, z, 0, 0, 0);
            z = __builtin_amdgcn_mfma_f32_16x16x32_bf16(kf1, qf1, z, 0, 0, 0);
            sacc[t] = z;
        }
        __builtin_amdgcn_s_setprio(0);

        // causal mask: only the diagonal tile needs it
        if (j == qt) {
#pragma unroll
            for (int t = 0; t < 4; ++t)
#pragma unroll
                for (int r = 0; r < 4; ++r) {
                    const int kv = j * 64 + t * 16 + lhi * 4 + r;
                    if (kv > qrow) sacc[t][r] = -1e30f;
                }
        }

        // per-lane partial max; cross-lane only on (rare) rescale
        float mt[4];
#pragma unroll
        for (int t = 0; t < 4; ++t)
            mt[t] = fmaxf(fmaxf(sacc[t][0], sacc[t][1]),
                          fmaxf(sacc[t][2], sacc[t][3]));
        const float pm = fmaxf(fmaxf(mt[0], mt[1]), fmaxf(mt[2], mt[3]));

        if (!__all(pm - mrun <= 8.0f)) {           // T13 defer-max
            float full = pm;
            full = fmaxf(full, __shfl_xor(full, 16));
            full = fmaxf(full, __shfl_xor(full, 32));
            const float mn = fmaxf(mrun, full);
            const float aa = exp2f(mrun - mn);
            mrun = mn;
            lpart *= aa;
            float ar[4];
#pragma unroll
            for (int r = 0; r < 4; ++r) ar[r] = __shfl(aa, lhi * 4 + r);
#pragma unroll
            for (int t = 0; t < 4; ++t)
#pragma unroll
                for (int r = 0; r < 4; ++r) o[t][r] *= ar[r];
        }

        // P = exp2(S - m), partial sum, pack to XOR-swizzled Pl
#pragma unroll
        for (int t = 0; t < 4; ++t) {
            bf16x4 pk;
#pragma unroll
            for (int r = 0; r < 4; ++r) {
                const float pv = exp2f(sacc[t][r] - mrun);
                lpart += pv;
                pk[r] = (__bf16)pv;
            }
            const int sw = (t * 4 + lhi) ^ pkey;   // 8B slot, swizzled
            *reinterpret_cast<bf16x4*>(&Pl[w][l15 * 64 + sw * 4]) = pk;
        }

        // O += P V
        bf16x8 pf0 = *reinterpret_cast<const bf16x8*>(
            &Pl[w][l15 * 64 + (((lhi * 2) ^ pkey) * 4)]);
        bf16x8 pf1 = *reinterpret_cast<const bf16x8*>(
            &Pl[w][l15 * 64 + (((8 + lhi * 2) ^ pkey) * 4)]);
        __builtin_amdgcn_s_setprio(1);
#pragma unroll
        for (int t = 0; t < 4; ++t) {
            const int rb = (t * 16 + l15) * 64;
            bf16x8 vf0 = *reinterpret_cast<const bf16x8*>(
                &Vl[cur][rb + ((lhi ^ rswz) * 8)]);
            bf16x8 vf1 = *reinterpret_cast<const bf16x8*>(
                &Vl[cur][rb + (((4 + lhi) ^ rswz) * 8)]);
            o[t] = __builtin_amdgcn_mfma_f32_16x16x32_bf16(pf0, vf0, o[t], 0, 0, 0);
            o[t] = __builtin_amdgcn_mfma_f32_16x16x32_bf16(pf1, vf1, o[t], 0, 0, 0);
        }
        __builtin_amdgcn_s_setprio(0);

        __syncthreads();   // drains gld16 prefetch + guards buffer reuse
    }

    // epilogue: combine partial sums, divide, store
    float ls = lpart;
    ls += __shfl_xor(ls, 16);
    ls += __shfl_xor(ls, 32);
    float lr[4];
#pragma unroll
    for (int r = 0; r < 4; ++r) lr[r] = __shfl(ls, lhi * 4 + r);
#pragma unroll
    for (int t = 0; t < 4; ++t)
#pragma unroll
        for (int r = 0; r < 4; ++r) {
            const float val = o[t][r] / lr[r];
            Y[(size_t)(qb + w * 16 + lhi * 4 + r) * DIM + h * HD + t * 16 + l15] =
                (__bf16)val;
        }
}

extern "C" void kernel_launch(void* const* d_in, const int* in_sizes, int n_in,
                              void* d_out, int out_size, void* d_ws, size_t ws_size,
                              hipStream_t stream) {
    const float* x    = (const float*)d_in[0];
    const float* fcos = (const float*)d_in[1];
    const float* fsin = (const float*)d_in[2];
    const float* wq   = (const float*)d_in[3];
    const float* wk   = (const float*)d_in[4];
    const float* wv   = (const float*)d_in[5];
    const float* wo   = (const float*)d_in[6];
    float* out = (float*)d_out;

    __bf16* xb    = (__bf16*)d_ws;                       // [2048][2048]
    __bf16* wqkvb = xb + (size_t)SEQ * DIM;              // [3072][2048]
    __bf16* wob   = wqkvb + (size_t)QKVD * DIM;          // [2048][2048]
    __bf16* QKVb  = wob + (size_t)DIM * DIM;             // [2048][3072]
    __bf16* Yb    = QKVb + (size_t)SEQ * QKVD;           // [2048][2048]
    __bf16* VTb   = Yb + (size_t)SEQ * DIM;              // [512][2048]

    const int nx  = SEQ * DIM / 4;
    const int nw  = DIM * DIM / 4;
    const int nkv = KVDIM * DIM / 4;
    cvt_f32_bf16<<<(nx + 255) / 256, 256, 0, stream>>>(x, xb, nx);
    cvt_f32_bf16<<<(nw + 255) / 256, 256, 0, stream>>>(wq, wqkvb, nw);
    cvt_f32_bf16<<<(nkv + 255) / 256, 256, 0, stream>>>(wk, wqkvb + (size_t)KOFF * DIM, nkv);
    cvt_f32_bf16<<<(nkv + 255) / 256, 256, 0, stream>>>(wv, wqkvb + (size_t)VOFF * DIM, nkv);
    cvt_f32_bf16<<<(nw + 255) / 256, 256, 0, stream>>>(wo, wob, nw);

    // fused QKV projection + RoPE epilogue; Q pre-scaled by 0.125*log2(e)
    gemm_tn<__bf16, true><<<dim3(QKVD / 64, SEQ / 128), 256, 0, stream>>>(
        xb, wqkvb, QKVb, SEQ, QKVD, DIM, 0.125f * 1.4426950408889634f, KOFF, fcos, fsin);

    transpose_v<<<dim3(SEQ / 64, KVDIM / 64), 256, 0, stream>>>(QKVb + VOFF, VTb);

    attn_kernel<<<dim3(1024), 256, 0, stream>>>(QKVb, VTb, Yb);

    gemm_tn<float, false><<<dim3(DIM / 64, SEQ / 128), 256, 0, stream>>>(
        Yb, wob, out, SEQ, DIM, DIM, 1.0f, 0, nullptr, nullptr);
}